// Round 1
// baseline (1131.036 us; speedup 1.0000x reference)
//
#include <hip/hip_runtime.h>

#define NCH 128
#define NGRAPH 64

// ---------------- CSR build ----------------

__global__ void k_count(const int* __restrict__ dst, int* __restrict__ cnt, int E) {
    int e = blockIdx.x * blockDim.x + threadIdx.x;
    if (e < E) atomicAdd(&cnt[dst[e]], 1);
}

__global__ void k_scan(const int* __restrict__ cnt, int* __restrict__ row_start, int N) {
    __shared__ int sums[1024];
    int tid = threadIdx.x;
    int chunk = (N + 1023) >> 10;
    int begin = tid * chunk;
    int end = begin + chunk; if (end > N) end = N;
    int s = 0;
    for (int i = begin; i < end; i++) s += cnt[i];
    sums[tid] = s;
    __syncthreads();
    for (int off = 1; off < 1024; off <<= 1) {
        int v = (tid >= off) ? sums[tid - off] : 0;
        __syncthreads();
        sums[tid] += v;
        __syncthreads();
    }
    int base = (tid == 0) ? 0 : sums[tid - 1];
    for (int i = begin; i < end; i++) { row_start[i] = base; base += cnt[i]; }
    if (tid == 1023) row_start[N] = sums[1023];
}

__global__ void k_dinv(const int* __restrict__ cnt, float* __restrict__ dinv, int N) {
    int i = blockIdx.x * blockDim.x + threadIdx.x;
    if (i < N) dinv[i] = rsqrtf((float)cnt[i] + 1.0f);
}

__global__ void k_fill(const int* __restrict__ src, const int* __restrict__ dst,
                       const float* __restrict__ dinv,
                       int* __restrict__ cursor, int* __restrict__ edge_src,
                       float* __restrict__ edge_w, int E) {
    int e = blockIdx.x * blockDim.x + threadIdx.x;
    if (e < E) {
        int s = src[e], d = dst[e];
        int p = atomicAdd(&cursor[d], 1);
        edge_src[p] = s;
        edge_w[p] = dinv[s] * dinv[d];
    }
}

// ---------------- GEMM: out[N,128] = H[N,128] @ W[128,128] ----------------

__global__ __launch_bounds__(256) void k_gemm(const float* __restrict__ H,
                                              const float* __restrict__ W,
                                              float* __restrict__ out, int N) {
    __shared__ float Wl[32 * 128];   // 16 KB k-tile of W
    __shared__ float Hl[16][128];    // 8 KB, 16 rows of H
    int t = threadIdx.x;
    int row0 = blockIdx.x * 16;

    // load 16 H rows
    #pragma unroll
    for (int i = 0; i < 8; i++) {
        int idx = t + i * 256;
        int r = idx >> 7, c = idx & 127;
        int gr = row0 + r;
        Hl[r][c] = (gr < N) ? H[gr * NCH + c] : 0.0f;
    }

    int col = t & 127, rg = t >> 7;   // 128 cols x 2 row-groups
    float acc[8] = {0, 0, 0, 0, 0, 0, 0, 0};

    for (int kt = 0; kt < 128; kt += 32) {
        __syncthreads();
        // load 32x128 W tile
        #pragma unroll
        for (int i = 0; i < 16; i++) {
            int idx = t + i * 256;
            int kk = idx >> 7, c = idx & 127;
            Wl[kk * 128 + c] = W[(kt + kk) * NCH + c];
        }
        __syncthreads();
        for (int k = 0; k < 32; k += 4) {
            float w0 = Wl[(k + 0) * 128 + col];
            float w1 = Wl[(k + 1) * 128 + col];
            float w2 = Wl[(k + 2) * 128 + col];
            float w3 = Wl[(k + 3) * 128 + col];
            #pragma unroll
            for (int r = 0; r < 8; r++) {
                const float4 h4 = *reinterpret_cast<const float4*>(&Hl[rg * 8 + r][kt + k]);
                acc[r] += h4.x * w0 + h4.y * w1 + h4.z * w2 + h4.w * w3;
            }
        }
    }

    #pragma unroll
    for (int r = 0; r < 8; r++) {
        int gr = row0 + rg * 8 + r;
        if (gr < N) out[gr * NCH + col] = acc[r];
    }
}

// ---------------- gather + self + bias + relu ----------------

__global__ __launch_bounds__(128) void k_gather(const float* __restrict__ hw,
                                                const float* __restrict__ bias,
                                                const int* __restrict__ row_start,
                                                const int* __restrict__ edge_src,
                                                const float* __restrict__ edge_w,
                                                const float* __restrict__ dinv,
                                                float* __restrict__ out, int N) {
    int n = blockIdx.x;
    int c = threadIdx.x;
    float dn = dinv[n];
    float acc = dn * dn * hw[n * NCH + c] + bias[c];
    int j0 = row_start[n], j1 = row_start[n + 1];
    for (int j = j0; j < j1; j++) {
        int s = edge_src[j];
        float w = edge_w[j];
        acc += w * hw[s * NCH + c];
    }
    out[n * NCH + c] = fmaxf(acc, 0.0f);
}

// ---------------- pooling ----------------

__global__ void k_batchcount(const int* __restrict__ batch, float* __restrict__ countsf, int N) {
    int i = blockIdx.x * blockDim.x + threadIdx.x;
    if (i < N) atomicAdd(&countsf[batch[i]], 1.0f);
}

__global__ __launch_bounds__(128) void k_pool(const float* __restrict__ h,
                                              const int* __restrict__ batch,
                                              float* __restrict__ pooled, int N) {
    int c = threadIdx.x;
    int n0 = blockIdx.x * 64;
    if (n0 >= N) return;
    int n1 = n0 + 64; if (n1 > N) n1 = N;
    int g = batch[n0];
    float acc = 0.0f;
    for (int n = n0; n < n1; n++) {
        int gn = batch[n];
        if (gn != g) { atomicAdd(&pooled[g * NCH + c], acc); acc = 0.0f; g = gn; }
        acc += h[n * NCH + c];
    }
    atomicAdd(&pooled[g * NCH + c], acc);
}

__global__ __launch_bounds__(128) void k_final(const float* __restrict__ pooled,
                                               const float* __restrict__ countsf,
                                               const float* __restrict__ Wc,
                                               const float* __restrict__ bc,
                                               float* __restrict__ out) {
    int t = threadIdx.x;           // 128 threads: 64 graphs x 2 outs
    int g = t >> 1, o = t & 1;
    float inv = 1.0f / fmaxf(countsf[g], 1.0f);
    float s = 0.0f;
    for (int k = 0; k < NCH; k++) s += pooled[g * NCH + k] * Wc[k * 2 + o];
    out[g * 2 + o] = s * inv + bc[o];
}

// ---------------- launcher ----------------

extern "C" void kernel_launch(void* const* d_in, const int* in_sizes, int n_in,
                              void* d_out, int out_size, void* d_ws, size_t ws_size,
                              hipStream_t stream) {
    const float* x   = (const float*)d_in[0];
    const int* eidx  = (const int*)d_in[1];
    const int* batch = (const int*)d_in[2];
    const float* W1 = (const float*)d_in[3];
    const float* b1 = (const float*)d_in[4];
    const float* W2 = (const float*)d_in[5];
    const float* b2 = (const float*)d_in[6];
    const float* W3 = (const float*)d_in[7];
    const float* b3 = (const float*)d_in[8];
    const float* Wc = (const float*)d_in[9];
    const float* bc = (const float*)d_in[10];
    float* out = (float*)d_out;

    int N = in_sizes[0] / NCH;
    int E = in_sizes[1] / 2;
    const int* src = eidx;
    const int* dst = eidx + E;

    // workspace carve-out (512B aligned)
    char* w = (char*)d_ws;
    auto alloc = [&](size_t bytes) -> void* {
        void* p = (void*)w;
        w += (bytes + 511) & ~(size_t)511;
        return p;
    };
    int*   cnt       = (int*)alloc((size_t)N * 4);
    int*   row_start = (int*)alloc((size_t)(N + 1) * 4);
    int*   cursor    = (int*)alloc((size_t)N * 4);
    int*   edge_src  = (int*)alloc((size_t)E * 4);
    float* edge_w    = (float*)alloc((size_t)E * 4);
    float* dinv      = (float*)alloc((size_t)N * 4);
    float* hw        = (float*)alloc((size_t)N * NCH * 4);
    float* hA        = (float*)alloc((size_t)N * NCH * 4);
    float* hB        = (float*)alloc((size_t)N * NCH * 4);
    float* pooled    = (float*)alloc((size_t)NGRAPH * NCH * 4);
    float* countsf   = (float*)alloc((size_t)NGRAPH * 4);

    hipMemsetAsync(cnt, 0, (size_t)N * 4, stream);
    hipMemsetAsync(pooled, 0, (size_t)NGRAPH * NCH * 4, stream);
    hipMemsetAsync(countsf, 0, (size_t)NGRAPH * 4, stream);

    int gE = (E + 255) / 256;
    int gN = (N + 255) / 256;

    k_count<<<gE, 256, 0, stream>>>(dst, cnt, E);
    k_scan<<<1, 1024, 0, stream>>>(cnt, row_start, N);
    k_dinv<<<gN, 256, 0, stream>>>(cnt, dinv, N);
    hipMemcpyAsync(cursor, row_start, (size_t)N * 4, hipMemcpyDeviceToDevice, stream);
    k_fill<<<gE, 256, 0, stream>>>(src, dst, dinv, cursor, edge_src, edge_w, E);

    int gG = (N + 15) / 16;
    // layer 1
    k_gemm<<<gG, 256, 0, stream>>>(x, W1, hw, N);
    k_gather<<<N, 128, 0, stream>>>(hw, b1, row_start, edge_src, edge_w, dinv, hA, N);
    // layer 2
    k_gemm<<<gG, 256, 0, stream>>>(hA, W2, hw, N);
    k_gather<<<N, 128, 0, stream>>>(hw, b2, row_start, edge_src, edge_w, dinv, hB, N);
    // layer 3
    k_gemm<<<gG, 256, 0, stream>>>(hB, W3, hw, N);
    k_gather<<<N, 128, 0, stream>>>(hw, b3, row_start, edge_src, edge_w, dinv, hA, N);

    k_batchcount<<<gN, 256, 0, stream>>>(batch, countsf, N);
    k_pool<<<(N + 63) / 64, 128, 0, stream>>>(hA, batch, pooled, N);
    k_final<<<1, 128, 0, stream>>>(pooled, countsf, Wc, bc, out);
}

// Round 2
// 860.037 us; speedup vs baseline: 1.3151x; 1.3151x over previous
//
#include <hip/hip_runtime.h>

#define NCH 128
#define NGRAPH 64

// ---------------- CSR build ----------------

__global__ void k_count(const int* __restrict__ dst, int* __restrict__ cnt, int E) {
    int e = blockIdx.x * blockDim.x + threadIdx.x;
    if (e < E) atomicAdd(&cnt[dst[e]], 1);
}

__global__ void k_scan(const int* __restrict__ cnt, int* __restrict__ row_start, int N) {
    __shared__ int sums[1024];
    int tid = threadIdx.x;
    int chunk = (N + 1023) >> 10;
    int begin = tid * chunk;
    int end = begin + chunk; if (end > N) end = N;
    int s = 0;
    for (int i = begin; i < end; i++) s += cnt[i];
    sums[tid] = s;
    __syncthreads();
    for (int off = 1; off < 1024; off <<= 1) {
        int v = (tid >= off) ? sums[tid - off] : 0;
        __syncthreads();
        sums[tid] += v;
        __syncthreads();
    }
    int base = (tid == 0) ? 0 : sums[tid - 1];
    for (int i = begin; i < end; i++) { row_start[i] = base; base += cnt[i]; }
    if (tid == 1023) row_start[N] = sums[1023];
}

__global__ void k_dinv(const int* __restrict__ cnt, float* __restrict__ dinv, int N) {
    int i = blockIdx.x * blockDim.x + threadIdx.x;
    if (i < N) dinv[i] = rsqrtf((float)cnt[i] + 1.0f);
}

__global__ void k_fill(const int* __restrict__ src, const int* __restrict__ dst,
                       const float* __restrict__ dinv,
                       int* __restrict__ cursor, int* __restrict__ edge_src,
                       float* __restrict__ edge_w, int E) {
    int e = blockIdx.x * blockDim.x + threadIdx.x;
    if (e < E) {
        int s = src[e], d = dst[e];
        int p = atomicAdd(&cursor[d], 1);
        edge_src[p] = s;
        edge_w[p] = dinv[s] * dinv[d];
    }
}

// ---------------- graph segment starts (batch is sorted -> no atomics) ----

__global__ void k_gstart(const int* __restrict__ batch, int* __restrict__ gstart, int N) {
    int i = blockIdx.x * blockDim.x + threadIdx.x;
    if (i >= N) return;
    int b = batch[i];
    int prev = (i == 0) ? -1 : batch[i - 1];
    for (int g = prev + 1; g <= b; g++) gstart[g] = i;
    if (i == N - 1) {
        for (int g = b + 1; g <= NGRAPH; g++) gstart[g] = N;
    }
}

// ---------------- GEMM: out[N,128] = H[N,128] @ W[128,128] ----------------

__global__ __launch_bounds__(256) void k_gemm(const float* __restrict__ H,
                                              const float* __restrict__ W,
                                              float* __restrict__ out, int N) {
    __shared__ float Wl[32 * 128];   // 16 KB k-tile of W
    __shared__ float Hl[16][128];    // 8 KB, 16 rows of H
    int t = threadIdx.x;
    int row0 = blockIdx.x * 16;

    // load 16 H rows
    #pragma unroll
    for (int i = 0; i < 8; i++) {
        int idx = t + i * 256;
        int r = idx >> 7, c = idx & 127;
        int gr = row0 + r;
        Hl[r][c] = (gr < N) ? H[gr * NCH + c] : 0.0f;
    }

    int col = t & 127, rg = t >> 7;   // 128 cols x 2 row-groups
    float acc[8] = {0, 0, 0, 0, 0, 0, 0, 0};

    for (int kt = 0; kt < 128; kt += 32) {
        __syncthreads();
        // load 32x128 W tile
        #pragma unroll
        for (int i = 0; i < 16; i++) {
            int idx = t + i * 256;
            int kk = idx >> 7, c = idx & 127;
            Wl[kk * 128 + c] = W[(kt + kk) * NCH + c];
        }
        __syncthreads();
        for (int k = 0; k < 32; k += 4) {
            float w0 = Wl[(k + 0) * 128 + col];
            float w1 = Wl[(k + 1) * 128 + col];
            float w2 = Wl[(k + 2) * 128 + col];
            float w3 = Wl[(k + 3) * 128 + col];
            #pragma unroll
            for (int r = 0; r < 8; r++) {
                const float4 h4 = *reinterpret_cast<const float4*>(&Hl[rg * 8 + r][kt + k]);
                acc[r] += h4.x * w0 + h4.y * w1 + h4.z * w2 + h4.w * w3;
            }
        }
    }

    #pragma unroll
    for (int r = 0; r < 8; r++) {
        int gr = row0 + rg * 8 + r;
        if (gr < N) out[gr * NCH + col] = acc[r];
    }
}

// ---------------- gather + self + bias + relu ----------------

__global__ __launch_bounds__(128) void k_gather(const float* __restrict__ hw,
                                                const float* __restrict__ bias,
                                                const int* __restrict__ row_start,
                                                const int* __restrict__ edge_src,
                                                const float* __restrict__ edge_w,
                                                const float* __restrict__ dinv,
                                                float* __restrict__ out, int N) {
    int n = blockIdx.x;
    int c = threadIdx.x;
    float dn = dinv[n];
    float acc = dn * dn * hw[n * NCH + c] + bias[c];
    int j0 = row_start[n], j1 = row_start[n + 1];
    for (int j = j0; j < j1; j++) {
        int s = edge_src[j];
        float w = edge_w[j];
        acc += w * hw[s * NCH + c];
    }
    out[n * NCH + c] = fmaxf(acc, 0.0f);
}

// ---------------- pooling: 1 block per graph, 4 row-lanes x 128 ch --------

__global__ __launch_bounds__(512) void k_pool(const float* __restrict__ h,
                                              const int* __restrict__ gstart,
                                              float* __restrict__ pooled) {
    __shared__ float sh[4][128];
    int g = blockIdx.x;
    int c = threadIdx.x & 127;
    int r = threadIdx.x >> 7;          // 0..3
    int j0 = gstart[g], j1 = gstart[g + 1];
    float acc = 0.0f;
    for (int j = j0 + r; j < j1; j += 4) acc += h[j * NCH + c];
    sh[r][c] = acc;
    __syncthreads();
    if (r == 0) {
        float s = sh[0][c] + sh[1][c] + sh[2][c] + sh[3][c];
        float inv = 1.0f / fmaxf((float)(j1 - j0), 1.0f);
        pooled[g * NCH + c] = s * inv;
    }
}

__global__ __launch_bounds__(128) void k_final(const float* __restrict__ pooled,
                                               const float* __restrict__ Wc,
                                               const float* __restrict__ bc,
                                               float* __restrict__ out) {
    int t = threadIdx.x;           // 128 threads: 64 graphs x 2 outs
    int g = t >> 1, o = t & 1;
    float s = 0.0f;
    for (int k = 0; k < NCH; k++) s += pooled[g * NCH + k] * Wc[k * 2 + o];
    out[g * 2 + o] = s + bc[o];
}

// ---------------- launcher ----------------

extern "C" void kernel_launch(void* const* d_in, const int* in_sizes, int n_in,
                              void* d_out, int out_size, void* d_ws, size_t ws_size,
                              hipStream_t stream) {
    const float* x   = (const float*)d_in[0];
    const int* eidx  = (const int*)d_in[1];
    const int* batch = (const int*)d_in[2];
    const float* W1 = (const float*)d_in[3];
    const float* b1 = (const float*)d_in[4];
    const float* W2 = (const float*)d_in[5];
    const float* b2 = (const float*)d_in[6];
    const float* W3 = (const float*)d_in[7];
    const float* b3 = (const float*)d_in[8];
    const float* Wc = (const float*)d_in[9];
    const float* bc = (const float*)d_in[10];
    float* out = (float*)d_out;

    int N = in_sizes[0] / NCH;
    int E = in_sizes[1] / 2;
    const int* src = eidx;
    const int* dst = eidx + E;

    // workspace carve-out (512B aligned)
    char* w = (char*)d_ws;
    auto alloc = [&](size_t bytes) -> void* {
        void* p = (void*)w;
        w += (bytes + 511) & ~(size_t)511;
        return p;
    };
    int*   cnt       = (int*)alloc((size_t)N * 4);
    int*   row_start = (int*)alloc((size_t)(N + 1) * 4);
    int*   cursor    = (int*)alloc((size_t)N * 4);
    int*   edge_src  = (int*)alloc((size_t)E * 4);
    float* edge_w    = (float*)alloc((size_t)E * 4);
    float* dinv      = (float*)alloc((size_t)N * 4);
    float* hw        = (float*)alloc((size_t)N * NCH * 4);
    float* hA        = (float*)alloc((size_t)N * NCH * 4);
    float* hB        = (float*)alloc((size_t)N * NCH * 4);
    float* pooled    = (float*)alloc((size_t)NGRAPH * NCH * 4);
    int*   gstart    = (int*)alloc((size_t)(NGRAPH + 1) * 4);

    hipMemsetAsync(cnt, 0, (size_t)N * 4, stream);

    int gE = (E + 255) / 256;
    int gN = (N + 255) / 256;

    k_count<<<gE, 256, 0, stream>>>(dst, cnt, E);
    k_scan<<<1, 1024, 0, stream>>>(cnt, row_start, N);
    k_dinv<<<gN, 256, 0, stream>>>(cnt, dinv, N);
    hipMemcpyAsync(cursor, row_start, (size_t)N * 4, hipMemcpyDeviceToDevice, stream);
    k_fill<<<gE, 256, 0, stream>>>(src, dst, dinv, cursor, edge_src, edge_w, E);
    k_gstart<<<gN, 256, 0, stream>>>(batch, gstart, N);

    int gG = (N + 15) / 16;
    // layer 1
    k_gemm<<<gG, 256, 0, stream>>>(x, W1, hw, N);
    k_gather<<<N, 128, 0, stream>>>(hw, b1, row_start, edge_src, edge_w, dinv, hA, N);
    // layer 2
    k_gemm<<<gG, 256, 0, stream>>>(hA, W2, hw, N);
    k_gather<<<N, 128, 0, stream>>>(hw, b2, row_start, edge_src, edge_w, dinv, hB, N);
    // layer 3
    k_gemm<<<gG, 256, 0, stream>>>(hB, W3, hw, N);
    k_gather<<<N, 128, 0, stream>>>(hw, b3, row_start, edge_src, edge_w, dinv, hA, N);

    k_pool<<<NGRAPH, 512, 0, stream>>>(hA, gstart, pooled);
    k_final<<<1, 128, 0, stream>>>(pooled, Wc, bc, out);
}

// Round 3
// 626.223 us; speedup vs baseline: 1.8061x; 1.3734x over previous
//
#include <hip/hip_runtime.h>

#define NCH 128
#define NGRAPH 64

// ---------------- CSR build ----------------

__global__ void k_count(const int* __restrict__ dst, int* __restrict__ cnt, int E) {
    int e = blockIdx.x * blockDim.x + threadIdx.x;
    if (e < E) atomicAdd(&cnt[dst[e]], 1);
}

__global__ void k_scan(const int* __restrict__ cnt, int* __restrict__ row_start, int N) {
    __shared__ int sums[1024];
    int tid = threadIdx.x;
    int chunk = (N + 1023) >> 10;
    int begin = tid * chunk;
    int end = begin + chunk; if (end > N) end = N;
    int s = 0;
    for (int i = begin; i < end; i++) s += cnt[i];
    sums[tid] = s;
    __syncthreads();
    for (int off = 1; off < 1024; off <<= 1) {
        int v = (tid >= off) ? sums[tid - off] : 0;
        __syncthreads();
        sums[tid] += v;
        __syncthreads();
    }
    int base = (tid == 0) ? 0 : sums[tid - 1];
    for (int i = begin; i < end; i++) { row_start[i] = base; base += cnt[i]; }
    if (tid == 1023) row_start[N] = sums[1023];
}

__global__ void k_dinv(const int* __restrict__ cnt, float* __restrict__ dinv, int N) {
    int i = blockIdx.x * blockDim.x + threadIdx.x;
    if (i < N) dinv[i] = rsqrtf((float)cnt[i] + 1.0f);
}

__global__ void k_fill(const int* __restrict__ src, const int* __restrict__ dst,
                       const float* __restrict__ dinv,
                       int* __restrict__ cursor, int* __restrict__ edge_src,
                       float* __restrict__ edge_w, int E) {
    int e = blockIdx.x * blockDim.x + threadIdx.x;
    if (e < E) {
        int s = src[e], d = dst[e];
        int p = atomicAdd(&cursor[d], 1);
        edge_src[p] = s;
        edge_w[p] = dinv[s] * dinv[d];
    }
}

// ---------------- graph segment starts (batch is sorted -> no atomics) ----

__global__ void k_gstart(const int* __restrict__ batch, int* __restrict__ gstart, int N) {
    int i = blockIdx.x * blockDim.x + threadIdx.x;
    if (i >= N) return;
    int b = batch[i];
    int prev = (i == 0) ? -1 : batch[i - 1];
    for (int g = prev + 1; g <= b; g++) gstart[g] = i;
    if (i == N - 1) {
        for (int g = b + 1; g <= NGRAPH; g++) gstart[g] = N;
    }
}

// ---------------- GEMM: out[N,128] = H[N,128] @ W[128,128] ----------------
// 128x128 tile per block, 256 threads, 8x8 register tile per thread.
// H staged transposed (Ht[k][r], pad 132 keeps b128 reads 16B-aligned).

#define KT 32

__global__ __launch_bounds__(256) void k_gemm(const float* __restrict__ H,
                                              const float* __restrict__ W,
                                              float* __restrict__ out, int N) {
    __shared__ float Ht[KT][132];
    __shared__ float Wl[KT][128];
    int t = threadIdx.x;
    int row0 = blockIdx.x * 128;
    int tc = t & 15, tr = t >> 4;      // 16x16 thread grid

    float acc[8][8];
    #pragma unroll
    for (int r = 0; r < 8; r++)
        #pragma unroll
        for (int c = 0; c < 8; c++) acc[r][c] = 0.0f;

    for (int kt = 0; kt < 128; kt += KT) {
        __syncthreads();
        // stage H tile (128 rows x 32 k) transposed: 4 float4 per thread
        #pragma unroll
        for (int i = 0; i < 4; i++) {
            int l = (i * 256 + t) * 4;        // 0..4095
            int r = l >> 5;                   // 32 floats per row chunk
            int kk = l & 31;
            int gr = row0 + r;
            float4 v = make_float4(0.f, 0.f, 0.f, 0.f);
            if (gr < N) v = *reinterpret_cast<const float4*>(&H[gr * NCH + kt + kk]);
            Ht[kk + 0][r] = v.x;
            Ht[kk + 1][r] = v.y;
            Ht[kk + 2][r] = v.z;
            Ht[kk + 3][r] = v.w;
        }
        // stage W tile (32 k x 128 cols): 4 float4 per thread
        #pragma unroll
        for (int i = 0; i < 4; i++) {
            int l = (i * 256 + t) * 4;
            int kk = l >> 7;
            int c = l & 127;
            *reinterpret_cast<float4*>(&Wl[kk][c]) =
                *reinterpret_cast<const float4*>(&W[(kt + kk) * NCH + c]);
        }
        __syncthreads();
        #pragma unroll
        for (int k = 0; k < KT; k++) {
            float hreg[8], wreg[8];
            *reinterpret_cast<float4*>(&hreg[0]) = *reinterpret_cast<const float4*>(&Ht[k][tr * 8]);
            *reinterpret_cast<float4*>(&hreg[4]) = *reinterpret_cast<const float4*>(&Ht[k][tr * 8 + 4]);
            *reinterpret_cast<float4*>(&wreg[0]) = *reinterpret_cast<const float4*>(&Wl[k][tc * 8]);
            *reinterpret_cast<float4*>(&wreg[4]) = *reinterpret_cast<const float4*>(&Wl[k][tc * 8 + 4]);
            #pragma unroll
            for (int r = 0; r < 8; r++)
                #pragma unroll
                for (int c = 0; c < 8; c++)
                    acc[r][c] += hreg[r] * wreg[c];
        }
    }

    #pragma unroll
    for (int r = 0; r < 8; r++) {
        int gr = row0 + tr * 8 + r;
        if (gr < N) {
            *reinterpret_cast<float4*>(&out[gr * NCH + tc * 8])     = *reinterpret_cast<float4*>(&acc[r][0]);
            *reinterpret_cast<float4*>(&out[gr * NCH + tc * 8 + 4]) = *reinterpret_cast<float4*>(&acc[r][4]);
        }
    }
}

// ---------------- gather + self + bias + relu ----------------

__global__ __launch_bounds__(128) void k_gather(const float* __restrict__ hw,
                                                const float* __restrict__ bias,
                                                const int* __restrict__ row_start,
                                                const int* __restrict__ edge_src,
                                                const float* __restrict__ edge_w,
                                                const float* __restrict__ dinv,
                                                float* __restrict__ out, int N) {
    int n = blockIdx.x;
    int c = threadIdx.x;
    float dn = dinv[n];
    float acc = dn * dn * hw[n * NCH + c] + bias[c];
    int j0 = row_start[n], j1 = row_start[n + 1];
    int j = j0;
    for (; j + 3 < j1; j += 4) {
        int s0 = edge_src[j + 0], s1 = edge_src[j + 1];
        int s2 = edge_src[j + 2], s3 = edge_src[j + 3];
        float w0 = edge_w[j + 0], w1 = edge_w[j + 1];
        float w2 = edge_w[j + 2], w3 = edge_w[j + 3];
        float h0 = hw[(size_t)s0 * NCH + c];
        float h1 = hw[(size_t)s1 * NCH + c];
        float h2 = hw[(size_t)s2 * NCH + c];
        float h3 = hw[(size_t)s3 * NCH + c];
        acc += w0 * h0 + w1 * h1 + w2 * h2 + w3 * h3;
    }
    for (; j < j1; j++) {
        acc += edge_w[j] * hw[(size_t)edge_src[j] * NCH + c];
    }
    out[n * NCH + c] = fmaxf(acc, 0.0f);
}

// ---------------- pooling: 1 block per graph, 4 row-lanes x 128 ch --------

__global__ __launch_bounds__(512) void k_pool(const float* __restrict__ h,
                                              const int* __restrict__ gstart,
                                              float* __restrict__ pooled) {
    __shared__ float sh[4][128];
    int g = blockIdx.x;
    int c = threadIdx.x & 127;
    int r = threadIdx.x >> 7;          // 0..3
    int j0 = gstart[g], j1 = gstart[g + 1];
    float acc = 0.0f;
    for (int j = j0 + r; j < j1; j += 4) acc += h[j * NCH + c];
    sh[r][c] = acc;
    __syncthreads();
    if (r == 0) {
        float s = sh[0][c] + sh[1][c] + sh[2][c] + sh[3][c];
        float inv = 1.0f / fmaxf((float)(j1 - j0), 1.0f);
        pooled[g * NCH + c] = s * inv;
    }
}

__global__ __launch_bounds__(128) void k_final(const float* __restrict__ pooled,
                                               const float* __restrict__ Wc,
                                               const float* __restrict__ bc,
                                               float* __restrict__ out) {
    int t = threadIdx.x;           // 128 threads: 64 graphs x 2 outs
    int g = t >> 1, o = t & 1;
    float s = 0.0f;
    for (int k = 0; k < NCH; k++) s += pooled[g * NCH + k] * Wc[k * 2 + o];
    out[g * 2 + o] = s + bc[o];
}

// ---------------- launcher ----------------

extern "C" void kernel_launch(void* const* d_in, const int* in_sizes, int n_in,
                              void* d_out, int out_size, void* d_ws, size_t ws_size,
                              hipStream_t stream) {
    const float* x   = (const float*)d_in[0];
    const int* eidx  = (const int*)d_in[1];
    const int* batch = (const int*)d_in[2];
    const float* W1 = (const float*)d_in[3];
    const float* b1 = (const float*)d_in[4];
    const float* W2 = (const float*)d_in[5];
    const float* b2 = (const float*)d_in[6];
    const float* W3 = (const float*)d_in[7];
    const float* b3 = (const float*)d_in[8];
    const float* Wc = (const float*)d_in[9];
    const float* bc = (const float*)d_in[10];
    float* out = (float*)d_out;

    int N = in_sizes[0] / NCH;
    int E = in_sizes[1] / 2;
    const int* src = eidx;
    const int* dst = eidx + E;

    // workspace carve-out (512B aligned)
    char* w = (char*)d_ws;
    auto alloc = [&](size_t bytes) -> void* {
        void* p = (void*)w;
        w += (bytes + 511) & ~(size_t)511;
        return p;
    };
    int*   cnt       = (int*)alloc((size_t)N * 4);
    int*   row_start = (int*)alloc((size_t)(N + 1) * 4);
    int*   cursor    = (int*)alloc((size_t)N * 4);
    int*   edge_src  = (int*)alloc((size_t)E * 4);
    float* edge_w    = (float*)alloc((size_t)E * 4);
    float* dinv      = (float*)alloc((size_t)N * 4);
    float* hw        = (float*)alloc((size_t)N * NCH * 4);
    float* hA        = (float*)alloc((size_t)N * NCH * 4);
    float* hB        = (float*)alloc((size_t)N * NCH * 4);
    float* pooled    = (float*)alloc((size_t)NGRAPH * NCH * 4);
    int*   gstart    = (int*)alloc((size_t)(NGRAPH + 1) * 4);

    hipMemsetAsync(cnt, 0, (size_t)N * 4, stream);

    int gE = (E + 255) / 256;
    int gN = (N + 255) / 256;

    k_count<<<gE, 256, 0, stream>>>(dst, cnt, E);
    k_scan<<<1, 1024, 0, stream>>>(cnt, row_start, N);
    k_dinv<<<gN, 256, 0, stream>>>(cnt, dinv, N);
    hipMemcpyAsync(cursor, row_start, (size_t)N * 4, hipMemcpyDeviceToDevice, stream);
    k_fill<<<gE, 256, 0, stream>>>(src, dst, dinv, cursor, edge_src, edge_w, E);
    k_gstart<<<gN, 256, 0, stream>>>(batch, gstart, N);

    int gG = (N + 127) / 128;
    // layer 1
    k_gemm<<<gG, 256, 0, stream>>>(x, W1, hw, N);
    k_gather<<<N, 128, 0, stream>>>(hw, b1, row_start, edge_src, edge_w, dinv, hA, N);
    // layer 2
    k_gemm<<<gG, 256, 0, stream>>>(hA, W2, hw, N);
    k_gather<<<N, 128, 0, stream>>>(hw, b2, row_start, edge_src, edge_w, dinv, hB, N);
    // layer 3
    k_gemm<<<gG, 256, 0, stream>>>(hB, W3, hw, N);
    k_gather<<<N, 128, 0, stream>>>(hw, b3, row_start, edge_src, edge_w, dinv, hA, N);

    k_pool<<<NGRAPH, 512, 0, stream>>>(hA, gstart, pooled);
    k_final<<<1, 128, 0, stream>>>(pooled, Wc, bc, out);
}

// Round 4
// 548.932 us; speedup vs baseline: 2.0604x; 1.1408x over previous
//
#include <hip/hip_runtime.h>

#define NCH 128
#define NGRAPH 64

// ---------------- CSR build ----------------

__global__ void k_count(const int* __restrict__ dst, int* __restrict__ cnt, int E) {
    int e = blockIdx.x * blockDim.x + threadIdx.x;
    if (e < E) atomicAdd(&cnt[dst[e]], 1);
}

// ---- 3-phase parallel exclusive scan over cnt[N] -> row_start[N+1] ----
// Phase A: per-block (1024 elems) sums.  Phase B: 1-wave scan of block sums.
// Phase C: block-local scan + offset, write row_start.

__global__ __launch_bounds__(256) void k_scanA(const int* __restrict__ cnt,
                                               int* __restrict__ blocksum, int N) {
    int base = blockIdx.x * 1024 + threadIdx.x * 4;
    int s = 0;
    #pragma unroll
    for (int i = 0; i < 4; i++) { int idx = base + i; if (idx < N) s += cnt[idx]; }
    for (int off = 32; off; off >>= 1) s += __shfl_down(s, off, 64);
    __shared__ int red[4];
    int lane = threadIdx.x & 63, wv = threadIdx.x >> 6;
    if (lane == 0) red[wv] = s;
    __syncthreads();
    if (threadIdx.x == 0) blocksum[blockIdx.x] = red[0] + red[1] + red[2] + red[3];
}

__global__ __launch_bounds__(64) void k_scanB(const int* __restrict__ blocksum,
                                              int* __restrict__ blockoff,
                                              int* __restrict__ row_start, int nb, int N) {
    int t = threadIdx.x;
    int v = (t < nb) ? blocksum[t] : 0;
    int orig = v;
    for (int off = 1; off < 64; off <<= 1) {
        int u = __shfl_up(v, off, 64);
        if (t >= off) v += u;
    }
    if (t < nb) blockoff[t] = v - orig;
    if (t == 63) row_start[N] = v;
}

__global__ __launch_bounds__(256) void k_scanC(const int* __restrict__ cnt,
                                               const int* __restrict__ blockoff,
                                               int* __restrict__ row_start, int N) {
    int t = threadIdx.x;
    int base = blockIdx.x * 1024 + t * 4;
    int v[4];
    #pragma unroll
    for (int i = 0; i < 4; i++) { int idx = base + i; v[i] = (idx < N) ? cnt[idx] : 0; }
    int tsum = v[0] + v[1] + v[2] + v[3];
    int sc = tsum;
    int lane = t & 63, wv = t >> 6;
    for (int off = 1; off < 64; off <<= 1) {
        int u = __shfl_up(sc, off, 64);
        if (lane >= off) sc += u;
    }
    int excl = sc - tsum;
    __shared__ int wsum[4];
    if (lane == 63) wsum[wv] = sc;
    __syncthreads();
    int woff = 0;
    for (int i = 0; i < wv; i++) woff += wsum[i];
    int off0 = blockoff[blockIdx.x] + woff + excl;
    #pragma unroll
    for (int i = 0; i < 4; i++) {
        int idx = base + i;
        if (idx < N) row_start[idx] = off0;
        off0 += v[i];
    }
}

__global__ void k_dinv(const int* __restrict__ cnt, float* __restrict__ dinv, int N) {
    int i = blockIdx.x * blockDim.x + threadIdx.x;
    if (i < N) dinv[i] = rsqrtf((float)cnt[i] + 1.0f);
}

__global__ void k_fill(const int* __restrict__ src, const int* __restrict__ dst,
                       const float* __restrict__ dinv,
                       int* __restrict__ cursor, int* __restrict__ edge_src,
                       float* __restrict__ edge_w, int E) {
    int e = blockIdx.x * blockDim.x + threadIdx.x;
    if (e < E) {
        int s = src[e], d = dst[e];
        int p = atomicAdd(&cursor[d], 1);
        edge_src[p] = s;
        edge_w[p] = dinv[s] * dinv[d];
    }
}

// ---------------- graph segment starts (batch is sorted -> no atomics) ----

__global__ void k_gstart(const int* __restrict__ batch, int* __restrict__ gstart, int N) {
    int i = blockIdx.x * blockDim.x + threadIdx.x;
    if (i >= N) return;
    int b = batch[i];
    int prev = (i == 0) ? -1 : batch[i - 1];
    for (int g = prev + 1; g <= b; g++) gstart[g] = i;
    if (i == N - 1) {
        for (int g = b + 1; g <= NGRAPH; g++) gstart[g] = N;
    }
}

// ---------------- GEMM: out[N,128] = H[N,128] @ W[128,128] ----------------
// 128x128 tile per block, 256 threads, 8x8 register tile per thread.

#define KT 32

__global__ __launch_bounds__(256) void k_gemm(const float* __restrict__ H,
                                              const float* __restrict__ W,
                                              float* __restrict__ out, int N) {
    __shared__ float Ht[KT][132];
    __shared__ float Wl[KT][128];
    int t = threadIdx.x;
    int row0 = blockIdx.x * 128;
    int tc = t & 15, tr = t >> 4;      // 16x16 thread grid

    float acc[8][8];
    #pragma unroll
    for (int r = 0; r < 8; r++)
        #pragma unroll
        for (int c = 0; c < 8; c++) acc[r][c] = 0.0f;

    for (int kt = 0; kt < 128; kt += KT) {
        __syncthreads();
        #pragma unroll
        for (int i = 0; i < 4; i++) {
            int l = (i * 256 + t) * 4;        // 0..4095
            int r = l >> 5;
            int kk = l & 31;
            int gr = row0 + r;
            float4 v = make_float4(0.f, 0.f, 0.f, 0.f);
            if (gr < N) v = *reinterpret_cast<const float4*>(&H[gr * NCH + kt + kk]);
            Ht[kk + 0][r] = v.x;
            Ht[kk + 1][r] = v.y;
            Ht[kk + 2][r] = v.z;
            Ht[kk + 3][r] = v.w;
        }
        #pragma unroll
        for (int i = 0; i < 4; i++) {
            int l = (i * 256 + t) * 4;
            int kk = l >> 7;
            int c = l & 127;
            *reinterpret_cast<float4*>(&Wl[kk][c]) =
                *reinterpret_cast<const float4*>(&W[(kt + kk) * NCH + c]);
        }
        __syncthreads();
        #pragma unroll
        for (int k = 0; k < KT; k++) {
            float hreg[8], wreg[8];
            *reinterpret_cast<float4*>(&hreg[0]) = *reinterpret_cast<const float4*>(&Ht[k][tr * 8]);
            *reinterpret_cast<float4*>(&hreg[4]) = *reinterpret_cast<const float4*>(&Ht[k][tr * 8 + 4]);
            *reinterpret_cast<float4*>(&wreg[0]) = *reinterpret_cast<const float4*>(&Wl[k][tc * 8]);
            *reinterpret_cast<float4*>(&wreg[4]) = *reinterpret_cast<const float4*>(&Wl[k][tc * 8 + 4]);
            #pragma unroll
            for (int r = 0; r < 8; r++)
                #pragma unroll
                for (int c = 0; c < 8; c++)
                    acc[r][c] += hreg[r] * wreg[c];
        }
    }

    #pragma unroll
    for (int r = 0; r < 8; r++) {
        int gr = row0 + tr * 8 + r;
        if (gr < N) {
            *reinterpret_cast<float4*>(&out[gr * NCH + tc * 8])     = *reinterpret_cast<float4*>(&acc[r][0]);
            *reinterpret_cast<float4*>(&out[gr * NCH + tc * 8 + 4]) = *reinterpret_cast<float4*>(&acc[r][4]);
        }
    }
}

// ---------------- gather + self + bias + relu ----------------

__global__ __launch_bounds__(128) void k_gather(const float* __restrict__ hw,
                                                const float* __restrict__ bias,
                                                const int* __restrict__ row_start,
                                                const int* __restrict__ edge_src,
                                                const float* __restrict__ edge_w,
                                                const float* __restrict__ dinv,
                                                float* __restrict__ out, int N) {
    int n = blockIdx.x;
    int c = threadIdx.x;
    float dn = dinv[n];
    float acc = dn * dn * hw[n * NCH + c] + bias[c];
    int j0 = row_start[n], j1 = row_start[n + 1];
    int j = j0;
    for (; j + 3 < j1; j += 4) {
        int s0 = edge_src[j + 0], s1 = edge_src[j + 1];
        int s2 = edge_src[j + 2], s3 = edge_src[j + 3];
        float w0 = edge_w[j + 0], w1 = edge_w[j + 1];
        float w2 = edge_w[j + 2], w3 = edge_w[j + 3];
        float h0 = hw[(size_t)s0 * NCH + c];
        float h1 = hw[(size_t)s1 * NCH + c];
        float h2 = hw[(size_t)s2 * NCH + c];
        float h3 = hw[(size_t)s3 * NCH + c];
        acc += w0 * h0 + w1 * h1 + w2 * h2 + w3 * h3;
    }
    for (; j < j1; j++) {
        acc += edge_w[j] * hw[(size_t)edge_src[j] * NCH + c];
    }
    out[n * NCH + c] = fmaxf(acc, 0.0f);
}

// ---------------- pooling: 1 block per graph, 4 row-lanes x 128 ch --------

__global__ __launch_bounds__(512) void k_pool(const float* __restrict__ h,
                                              const int* __restrict__ gstart,
                                              float* __restrict__ pooled) {
    __shared__ float sh[4][128];
    int g = blockIdx.x;
    int c = threadIdx.x & 127;
    int r = threadIdx.x >> 7;          // 0..3
    int j0 = gstart[g], j1 = gstart[g + 1];
    float acc = 0.0f;
    for (int j = j0 + r; j < j1; j += 4) acc += h[j * NCH + c];
    sh[r][c] = acc;
    __syncthreads();
    if (r == 0) {
        float s = sh[0][c] + sh[1][c] + sh[2][c] + sh[3][c];
        float inv = 1.0f / fmaxf((float)(j1 - j0), 1.0f);
        pooled[g * NCH + c] = s * inv;
    }
}

__global__ __launch_bounds__(128) void k_final(const float* __restrict__ pooled,
                                               const float* __restrict__ Wc,
                                               const float* __restrict__ bc,
                                               float* __restrict__ out) {
    int t = threadIdx.x;           // 128 threads: 64 graphs x 2 outs
    int g = t >> 1, o = t & 1;
    float s = 0.0f;
    for (int k = 0; k < NCH; k++) s += pooled[g * NCH + k] * Wc[k * 2 + o];
    out[g * 2 + o] = s + bc[o];
}

// ---------------- launcher ----------------

extern "C" void kernel_launch(void* const* d_in, const int* in_sizes, int n_in,
                              void* d_out, int out_size, void* d_ws, size_t ws_size,
                              hipStream_t stream) {
    const float* x   = (const float*)d_in[0];
    const int* eidx  = (const int*)d_in[1];
    const int* batch = (const int*)d_in[2];
    const float* W1 = (const float*)d_in[3];
    const float* b1 = (const float*)d_in[4];
    const float* W2 = (const float*)d_in[5];
    const float* b2 = (const float*)d_in[6];
    const float* W3 = (const float*)d_in[7];
    const float* b3 = (const float*)d_in[8];
    const float* Wc = (const float*)d_in[9];
    const float* bc = (const float*)d_in[10];
    float* out = (float*)d_out;

    int N = in_sizes[0] / NCH;
    int E = in_sizes[1] / 2;
    const int* src = eidx;
    const int* dst = eidx + E;

    // workspace carve-out (512B aligned)
    char* w = (char*)d_ws;
    auto alloc = [&](size_t bytes) -> void* {
        void* p = (void*)w;
        w += (bytes + 511) & ~(size_t)511;
        return p;
    };
    int nb = (N + 1023) / 1024;
    int*   cnt       = (int*)alloc((size_t)N * 4);
    int*   row_start = (int*)alloc((size_t)(N + 1) * 4);
    int*   cursor    = (int*)alloc((size_t)N * 4);
    int*   blocksum  = (int*)alloc((size_t)nb * 4);
    int*   blockoff  = (int*)alloc((size_t)nb * 4);
    int*   edge_src  = (int*)alloc((size_t)E * 4);
    float* edge_w    = (float*)alloc((size_t)E * 4);
    float* dinv      = (float*)alloc((size_t)N * 4);
    float* hw        = (float*)alloc((size_t)N * NCH * 4);
    float* hA        = (float*)alloc((size_t)N * NCH * 4);
    float* hB        = (float*)alloc((size_t)N * NCH * 4);
    float* pooled    = (float*)alloc((size_t)NGRAPH * NCH * 4);
    int*   gstart    = (int*)alloc((size_t)(NGRAPH + 1) * 4);

    hipMemsetAsync(cnt, 0, (size_t)N * 4, stream);

    int gE = (E + 255) / 256;
    int gN = (N + 255) / 256;

    k_count<<<gE, 256, 0, stream>>>(dst, cnt, E);
    k_scanA<<<nb, 256, 0, stream>>>(cnt, blocksum, N);
    k_scanB<<<1, 64, 0, stream>>>(blocksum, blockoff, row_start, nb, N);
    k_scanC<<<nb, 256, 0, stream>>>(cnt, blockoff, row_start, N);
    k_dinv<<<gN, 256, 0, stream>>>(cnt, dinv, N);
    hipMemcpyAsync(cursor, row_start, (size_t)N * 4, hipMemcpyDeviceToDevice, stream);
    k_fill<<<gE, 256, 0, stream>>>(src, dst, dinv, cursor, edge_src, edge_w, E);
    k_gstart<<<gN, 256, 0, stream>>>(batch, gstart, N);

    int gG = (N + 127) / 128;
    // layer 1
    k_gemm<<<gG, 256, 0, stream>>>(x, W1, hw, N);
    k_gather<<<N, 128, 0, stream>>>(hw, b1, row_start, edge_src, edge_w, dinv, hA, N);
    // layer 2
    k_gemm<<<gG, 256, 0, stream>>>(hA, W2, hw, N);
    k_gather<<<N, 128, 0, stream>>>(hw, b2, row_start, edge_src, edge_w, dinv, hB, N);
    // layer 3
    k_gemm<<<gG, 256, 0, stream>>>(hB, W3, hw, N);
    k_gather<<<N, 128, 0, stream>>>(hw, b3, row_start, edge_src, edge_w, dinv, hA, N);

    k_pool<<<NGRAPH, 512, 0, stream>>>(hA, gstart, pooled);
    k_final<<<1, 128, 0, stream>>>(pooled, Wc, bc, out);
}

// Round 5
// 503.738 us; speedup vs baseline: 2.2453x; 1.0897x over previous
//
#include <hip/hip_runtime.h>

#define NCH 128
#define NGRAPH 64
#define SUB 16

// ---------------- CSR build ----------------

__global__ void k_count(const int* __restrict__ dst, int* __restrict__ cnt, int E) {
    int e = blockIdx.x * blockDim.x + threadIdx.x;
    if (e < E) atomicAdd(&cnt[dst[e]], 1);
}

// ---- 3-phase parallel exclusive scan over cnt[N] -> row_start[N+1] ----

__global__ __launch_bounds__(256) void k_scanA(const int* __restrict__ cnt,
                                               int* __restrict__ blocksum, int N) {
    int base = blockIdx.x * 1024 + threadIdx.x * 4;
    int s = 0;
    #pragma unroll
    for (int i = 0; i < 4; i++) { int idx = base + i; if (idx < N) s += cnt[idx]; }
    for (int off = 32; off; off >>= 1) s += __shfl_down(s, off, 64);
    __shared__ int red[4];
    int lane = threadIdx.x & 63, wv = threadIdx.x >> 6;
    if (lane == 0) red[wv] = s;
    __syncthreads();
    if (threadIdx.x == 0) blocksum[blockIdx.x] = red[0] + red[1] + red[2] + red[3];
}

__global__ __launch_bounds__(64) void k_scanB(const int* __restrict__ blocksum,
                                              int* __restrict__ blockoff,
                                              int* __restrict__ row_start, int nb, int N) {
    int t = threadIdx.x;
    int v = (t < nb) ? blocksum[t] : 0;
    int orig = v;
    for (int off = 1; off < 64; off <<= 1) {
        int u = __shfl_up(v, off, 64);
        if (t >= off) v += u;
    }
    if (t < nb) blockoff[t] = v - orig;
    if (t == 63) row_start[N] = v;
}

__global__ __launch_bounds__(256) void k_scanC(const int* __restrict__ cnt,
                                               const int* __restrict__ blockoff,
                                               int* __restrict__ row_start, int N) {
    int t = threadIdx.x;
    int base = blockIdx.x * 1024 + t * 4;
    int v[4];
    #pragma unroll
    for (int i = 0; i < 4; i++) { int idx = base + i; v[i] = (idx < N) ? cnt[idx] : 0; }
    int tsum = v[0] + v[1] + v[2] + v[3];
    int sc = tsum;
    int lane = t & 63, wv = t >> 6;
    for (int off = 1; off < 64; off <<= 1) {
        int u = __shfl_up(sc, off, 64);
        if (lane >= off) sc += u;
    }
    int excl = sc - tsum;
    __shared__ int wsum[4];
    if (lane == 63) wsum[wv] = sc;
    __syncthreads();
    int woff = 0;
    for (int i = 0; i < wv; i++) woff += wsum[i];
    int off0 = blockoff[blockIdx.x] + woff + excl;
    #pragma unroll
    for (int i = 0; i < 4; i++) {
        int idx = base + i;
        if (idx < N) row_start[idx] = off0;
        off0 += v[i];
    }
}

__global__ void k_dinv(const int* __restrict__ cnt, float* __restrict__ dinv, int N) {
    int i = blockIdx.x * blockDim.x + threadIdx.x;
    if (i < N) dinv[i] = rsqrtf((float)cnt[i] + 1.0f);
}

__global__ void k_fill(const int* __restrict__ src, const int* __restrict__ dst,
                       const float* __restrict__ dinv,
                       int* __restrict__ cursor, int* __restrict__ edge_src,
                       float* __restrict__ edge_w, int E) {
    int e = blockIdx.x * blockDim.x + threadIdx.x;
    if (e < E) {
        int s = src[e], d = dst[e];
        int p = atomicAdd(&cursor[d], 1);
        edge_src[p] = s;
        edge_w[p] = dinv[s] * dinv[d];
    }
}

// ---------------- graph segment starts (batch is sorted -> no atomics) ----

__global__ void k_gstart(const int* __restrict__ batch, int* __restrict__ gstart, int N) {
    int i = blockIdx.x * blockDim.x + threadIdx.x;
    if (i >= N) return;
    int b = batch[i];
    int prev = (i == 0) ? -1 : batch[i - 1];
    for (int g = prev + 1; g <= b; g++) gstart[g] = i;
    if (i == N - 1) {
        for (int g = b + 1; g <= NGRAPH; g++) gstart[g] = N;
    }
}

// ---------------- GEMM: out[N,128] = H[N,128] @ W[128,128] ----------------

#define KT 32

__global__ __launch_bounds__(256) void k_gemm(const float* __restrict__ H,
                                              const float* __restrict__ W,
                                              float* __restrict__ out, int N) {
    __shared__ float Ht[KT][132];
    __shared__ float Wl[KT][128];
    int t = threadIdx.x;
    int row0 = blockIdx.x * 128;
    int tc = t & 15, tr = t >> 4;      // 16x16 thread grid

    float acc[8][8];
    #pragma unroll
    for (int r = 0; r < 8; r++)
        #pragma unroll
        for (int c = 0; c < 8; c++) acc[r][c] = 0.0f;

    for (int kt = 0; kt < 128; kt += KT) {
        __syncthreads();
        #pragma unroll
        for (int i = 0; i < 4; i++) {
            int l = (i * 256 + t) * 4;        // 0..4095
            int r = l >> 5;
            int kk = l & 31;
            int gr = row0 + r;
            float4 v = make_float4(0.f, 0.f, 0.f, 0.f);
            if (gr < N) v = *reinterpret_cast<const float4*>(&H[gr * NCH + kt + kk]);
            Ht[kk + 0][r] = v.x;
            Ht[kk + 1][r] = v.y;
            Ht[kk + 2][r] = v.z;
            Ht[kk + 3][r] = v.w;
        }
        #pragma unroll
        for (int i = 0; i < 4; i++) {
            int l = (i * 256 + t) * 4;
            int kk = l >> 7;
            int c = l & 127;
            *reinterpret_cast<float4*>(&Wl[kk][c]) =
                *reinterpret_cast<const float4*>(&W[(kt + kk) * NCH + c]);
        }
        __syncthreads();
        #pragma unroll
        for (int k = 0; k < KT; k++) {
            float hreg[8], wreg[8];
            *reinterpret_cast<float4*>(&hreg[0]) = *reinterpret_cast<const float4*>(&Ht[k][tr * 8]);
            *reinterpret_cast<float4*>(&hreg[4]) = *reinterpret_cast<const float4*>(&Ht[k][tr * 8 + 4]);
            *reinterpret_cast<float4*>(&wreg[0]) = *reinterpret_cast<const float4*>(&Wl[k][tc * 8]);
            *reinterpret_cast<float4*>(&wreg[4]) = *reinterpret_cast<const float4*>(&Wl[k][tc * 8 + 4]);
            #pragma unroll
            for (int r = 0; r < 8; r++)
                #pragma unroll
                for (int c = 0; c < 8; c++)
                    acc[r][c] += hreg[r] * wreg[c];
        }
    }

    #pragma unroll
    for (int r = 0; r < 8; r++) {
        int gr = row0 + tr * 8 + r;
        if (gr < N) {
            *reinterpret_cast<float4*>(&out[gr * NCH + tc * 8])     = *reinterpret_cast<float4*>(&acc[r][0]);
            *reinterpret_cast<float4*>(&out[gr * NCH + tc * 8 + 4]) = *reinterpret_cast<float4*>(&acc[r][4]);
        }
    }
}

// ---------------- gather + self + bias + relu ----------------

__global__ __launch_bounds__(128) void k_gather(const float* __restrict__ hw,
                                                const float* __restrict__ bias,
                                                const int* __restrict__ row_start,
                                                const int* __restrict__ edge_src,
                                                const float* __restrict__ edge_w,
                                                const float* __restrict__ dinv,
                                                float* __restrict__ out, int N) {
    int n = blockIdx.x;
    int c = threadIdx.x;
    float dn = dinv[n];
    float acc = dn * dn * hw[n * NCH + c] + bias[c];
    int j0 = row_start[n], j1 = row_start[n + 1];
    int j = j0;
    for (; j + 3 < j1; j += 4) {
        int s0 = edge_src[j + 0], s1 = edge_src[j + 1];
        int s2 = edge_src[j + 2], s3 = edge_src[j + 3];
        float w0 = edge_w[j + 0], w1 = edge_w[j + 1];
        float w2 = edge_w[j + 2], w3 = edge_w[j + 3];
        float h0 = hw[(size_t)s0 * NCH + c];
        float h1 = hw[(size_t)s1 * NCH + c];
        float h2 = hw[(size_t)s2 * NCH + c];
        float h3 = hw[(size_t)s3 * NCH + c];
        acc += w0 * h0 + w1 * h1 + w2 * h2 + w3 * h3;
    }
    for (; j < j1; j++) {
        acc += edge_w[j] * hw[(size_t)edge_src[j] * NCH + c];
    }
    out[n * NCH + c] = fmaxf(acc, 0.0f);
}

// ---------------- pooling: 2-phase, 64*SUB blocks then 64 blocks ----------

__global__ __launch_bounds__(256) void k_poolA(const float* __restrict__ h,
                                               const int* __restrict__ gstart,
                                               float* __restrict__ partial) {
    int g = blockIdx.x >> 4;           // / SUB
    int s = blockIdx.x & (SUB - 1);
    int c = threadIdx.x & 127;
    int r = threadIdx.x >> 7;          // 0..1
    int j0 = gstart[g], j1 = gstart[g + 1];
    int len = j1 - j0;
    int chunk = (len + SUB - 1) / SUB;
    int a0 = j0 + s * chunk;
    int a1 = a0 + chunk; if (a1 > j1) a1 = j1;
    float acc = 0.0f;
    for (int j = a0 + r; j < a1; j += 2) acc += h[(size_t)j * NCH + c];
    __shared__ float sh[2][128];
    sh[r][c] = acc;
    __syncthreads();
    if (r == 0) partial[(size_t)(g * SUB + s) * NCH + c] = sh[0][c] + sh[1][c];
}

__global__ __launch_bounds__(128) void k_poolB(const float* __restrict__ partial,
                                               const int* __restrict__ gstart,
                                               float* __restrict__ pooled) {
    int g = blockIdx.x;
    int c = threadIdx.x;
    float s = 0.0f;
    #pragma unroll
    for (int i = 0; i < SUB; i++) s += partial[(size_t)(g * SUB + i) * NCH + c];
    int len = gstart[g + 1] - gstart[g];
    pooled[g * NCH + c] = s / fmaxf((float)len, 1.0f);
}

__global__ __launch_bounds__(128) void k_final(const float* __restrict__ pooled,
                                               const float* __restrict__ Wc,
                                               const float* __restrict__ bc,
                                               float* __restrict__ out) {
    int t = threadIdx.x;           // 128 threads: 64 graphs x 2 outs
    int g = t >> 1, o = t & 1;
    float s = 0.0f;
    for (int k = 0; k < NCH; k++) s += pooled[g * NCH + k] * Wc[k * 2 + o];
    out[g * 2 + o] = s + bc[o];
}

// ---------------- launcher ----------------

extern "C" void kernel_launch(void* const* d_in, const int* in_sizes, int n_in,
                              void* d_out, int out_size, void* d_ws, size_t ws_size,
                              hipStream_t stream) {
    const float* x   = (const float*)d_in[0];
    const int* eidx  = (const int*)d_in[1];
    const int* batch = (const int*)d_in[2];
    const float* W1 = (const float*)d_in[3];
    const float* b1 = (const float*)d_in[4];
    const float* W2 = (const float*)d_in[5];
    const float* b2 = (const float*)d_in[6];
    const float* W3 = (const float*)d_in[7];
    const float* b3 = (const float*)d_in[8];
    const float* Wc = (const float*)d_in[9];
    const float* bc = (const float*)d_in[10];
    float* out = (float*)d_out;

    int N = in_sizes[0] / NCH;
    int E = in_sizes[1] / 2;
    const int* src = eidx;
    const int* dst = eidx + E;

    // workspace carve-out (512B aligned)
    char* w = (char*)d_ws;
    auto alloc = [&](size_t bytes) -> void* {
        void* p = (void*)w;
        w += (bytes + 511) & ~(size_t)511;
        return p;
    };
    int nb = (N + 1023) / 1024;
    int*   cnt       = (int*)alloc((size_t)N * 4);
    int*   row_start = (int*)alloc((size_t)(N + 1) * 4);
    int*   cursor    = (int*)alloc((size_t)N * 4);
    int*   blocksum  = (int*)alloc((size_t)nb * 4);
    int*   blockoff  = (int*)alloc((size_t)nb * 4);
    int*   edge_src  = (int*)alloc((size_t)E * 4);
    float* edge_w    = (float*)alloc((size_t)E * 4);
    float* dinv      = (float*)alloc((size_t)N * 4);
    float* hw        = (float*)alloc((size_t)N * NCH * 4);
    float* hA        = (float*)alloc((size_t)N * NCH * 4);
    float* hB        = (float*)alloc((size_t)N * NCH * 4);
    float* partial   = (float*)alloc((size_t)NGRAPH * SUB * NCH * 4);
    float* pooled    = (float*)alloc((size_t)NGRAPH * NCH * 4);
    int*   gstart    = (int*)alloc((size_t)(NGRAPH + 1) * 4);

    hipMemsetAsync(cnt, 0, (size_t)N * 4, stream);

    int gE = (E + 255) / 256;
    int gN = (N + 255) / 256;

    k_count<<<gE, 256, 0, stream>>>(dst, cnt, E);
    k_scanA<<<nb, 256, 0, stream>>>(cnt, blocksum, N);
    k_scanB<<<1, 64, 0, stream>>>(blocksum, blockoff, row_start, nb, N);
    k_scanC<<<nb, 256, 0, stream>>>(cnt, blockoff, row_start, N);
    k_dinv<<<gN, 256, 0, stream>>>(cnt, dinv, N);
    hipMemcpyAsync(cursor, row_start, (size_t)N * 4, hipMemcpyDeviceToDevice, stream);
    k_fill<<<gE, 256, 0, stream>>>(src, dst, dinv, cursor, edge_src, edge_w, E);
    k_gstart<<<gN, 256, 0, stream>>>(batch, gstart, N);

    int gG = (N + 127) / 128;
    // layer 1
    k_gemm<<<gG, 256, 0, stream>>>(x, W1, hw, N);
    k_gather<<<N, 128, 0, stream>>>(hw, b1, row_start, edge_src, edge_w, dinv, hA, N);
    // layer 2
    k_gemm<<<gG, 256, 0, stream>>>(hA, W2, hw, N);
    k_gather<<<N, 128, 0, stream>>>(hw, b2, row_start, edge_src, edge_w, dinv, hB, N);
    // layer 3
    k_gemm<<<gG, 256, 0, stream>>>(hB, W3, hw, N);
    k_gather<<<N, 128, 0, stream>>>(hw, b3, row_start, edge_src, edge_w, dinv, hA, N);

    k_poolA<<<NGRAPH * SUB, 256, 0, stream>>>(hA, gstart, partial);
    k_poolB<<<NGRAPH, 128, 0, stream>>>(partial, gstart, pooled);
    k_final<<<1, 128, 0, stream>>>(pooled, Wc, bc, out);
}

// Round 6
// 470.248 us; speedup vs baseline: 2.4052x; 1.0712x over previous
//
#include <hip/hip_runtime.h>

#define NCH 128
#define NGRAPH 64
#define SUB 16

// ---------------- CSR build ----------------

__global__ void k_count(const int* __restrict__ dst, int* __restrict__ cnt, int E) {
    int e = blockIdx.x * blockDim.x + threadIdx.x;
    if (e < E) atomicAdd(&cnt[dst[e]], 1);
}

// ---- 3-phase parallel exclusive scan over cnt[N] -> row_start[N+1] ----

__global__ __launch_bounds__(256) void k_scanA(const int* __restrict__ cnt,
                                               int* __restrict__ blocksum, int N) {
    int base = blockIdx.x * 1024 + threadIdx.x * 4;
    int s = 0;
    #pragma unroll
    for (int i = 0; i < 4; i++) { int idx = base + i; if (idx < N) s += cnt[idx]; }
    for (int off = 32; off; off >>= 1) s += __shfl_down(s, off, 64);
    __shared__ int red[4];
    int lane = threadIdx.x & 63, wv = threadIdx.x >> 6;
    if (lane == 0) red[wv] = s;
    __syncthreads();
    if (threadIdx.x == 0) blocksum[blockIdx.x] = red[0] + red[1] + red[2] + red[3];
}

__global__ __launch_bounds__(64) void k_scanB(const int* __restrict__ blocksum,
                                              int* __restrict__ blockoff,
                                              int* __restrict__ row_start, int nb, int N) {
    int t = threadIdx.x;
    int v = (t < nb) ? blocksum[t] : 0;
    int orig = v;
    for (int off = 1; off < 64; off <<= 1) {
        int u = __shfl_up(v, off, 64);
        if (t >= off) v += u;
    }
    if (t < nb) blockoff[t] = v - orig;
    if (t == 63) row_start[N] = v;
}

__global__ __launch_bounds__(256) void k_scanC(const int* __restrict__ cnt,
                                               const int* __restrict__ blockoff,
                                               int* __restrict__ row_start, int N) {
    int t = threadIdx.x;
    int base = blockIdx.x * 1024 + t * 4;
    int v[4];
    #pragma unroll
    for (int i = 0; i < 4; i++) { int idx = base + i; v[i] = (idx < N) ? cnt[idx] : 0; }
    int tsum = v[0] + v[1] + v[2] + v[3];
    int sc = tsum;
    int lane = t & 63, wv = t >> 6;
    for (int off = 1; off < 64; off <<= 1) {
        int u = __shfl_up(sc, off, 64);
        if (lane >= off) sc += u;
    }
    int excl = sc - tsum;
    __shared__ int wsum[4];
    if (lane == 63) wsum[wv] = sc;
    __syncthreads();
    int woff = 0;
    for (int i = 0; i < wv; i++) woff += wsum[i];
    int off0 = blockoff[blockIdx.x] + woff + excl;
    #pragma unroll
    for (int i = 0; i < 4; i++) {
        int idx = base + i;
        if (idx < N) row_start[idx] = off0;
        off0 += v[i];
    }
}

__global__ void k_dinv(const int* __restrict__ cnt, float* __restrict__ dinv, int N) {
    int i = blockIdx.x * blockDim.x + threadIdx.x;
    if (i < N) dinv[i] = rsqrtf((float)cnt[i] + 1.0f);
}

// scatter only the source index (single 4B store per edge)
__global__ void k_fill(const int* __restrict__ src, const int* __restrict__ dst,
                       int* __restrict__ cursor, int* __restrict__ edge_src, int E) {
    int e = blockIdx.x * blockDim.x + threadIdx.x;
    if (e < E) {
        int p = atomicAdd(&cursor[dst[e]], 1);
        edge_src[p] = src[e];
    }
}

// ---------------- graph segment starts (batch is sorted -> no atomics) ----

__global__ void k_gstart(const int* __restrict__ batch, int* __restrict__ gstart, int N) {
    int i = blockIdx.x * blockDim.x + threadIdx.x;
    if (i >= N) return;
    int b = batch[i];
    int prev = (i == 0) ? -1 : batch[i - 1];
    for (int g = prev + 1; g <= b; g++) gstart[g] = i;
    if (i == N - 1) {
        for (int g = b + 1; g <= NGRAPH; g++) gstart[g] = N;
    }
}

// ------- GEMM: out[N,128] = dinv[r] * (H[N,128] @ W[128,128]) -------------
// 128x128 tile per block, 256 threads, 8x8 register tile per thread.
// The dinv row-scale in the epilogue folds the GCN edge norm into the
// features: gather then needs NO per-edge weight at all.

#define KT 32

__global__ __launch_bounds__(256) void k_gemm(const float* __restrict__ H,
                                              const float* __restrict__ W,
                                              const float* __restrict__ dinv,
                                              float* __restrict__ out, int N) {
    __shared__ float Ht[KT][132];
    __shared__ float Wl[KT][128];
    int t = threadIdx.x;
    int row0 = blockIdx.x * 128;
    int tc = t & 15, tr = t >> 4;      // 16x16 thread grid

    float acc[8][8];
    #pragma unroll
    for (int r = 0; r < 8; r++)
        #pragma unroll
        for (int c = 0; c < 8; c++) acc[r][c] = 0.0f;

    for (int kt = 0; kt < 128; kt += KT) {
        __syncthreads();
        #pragma unroll
        for (int i = 0; i < 4; i++) {
            int l = (i * 256 + t) * 4;        // 0..4095
            int r = l >> 5;
            int kk = l & 31;
            int gr = row0 + r;
            float4 v = make_float4(0.f, 0.f, 0.f, 0.f);
            if (gr < N) v = *reinterpret_cast<const float4*>(&H[gr * NCH + kt + kk]);
            Ht[kk + 0][r] = v.x;
            Ht[kk + 1][r] = v.y;
            Ht[kk + 2][r] = v.z;
            Ht[kk + 3][r] = v.w;
        }
        #pragma unroll
        for (int i = 0; i < 4; i++) {
            int l = (i * 256 + t) * 4;
            int kk = l >> 7;
            int c = l & 127;
            *reinterpret_cast<float4*>(&Wl[kk][c]) =
                *reinterpret_cast<const float4*>(&W[(kt + kk) * NCH + c]);
        }
        __syncthreads();
        #pragma unroll
        for (int k = 0; k < KT; k++) {
            float hreg[8], wreg[8];
            *reinterpret_cast<float4*>(&hreg[0]) = *reinterpret_cast<const float4*>(&Ht[k][tr * 8]);
            *reinterpret_cast<float4*>(&hreg[4]) = *reinterpret_cast<const float4*>(&Ht[k][tr * 8 + 4]);
            *reinterpret_cast<float4*>(&wreg[0]) = *reinterpret_cast<const float4*>(&Wl[k][tc * 8]);
            *reinterpret_cast<float4*>(&wreg[4]) = *reinterpret_cast<const float4*>(&Wl[k][tc * 8 + 4]);
            #pragma unroll
            for (int r = 0; r < 8; r++)
                #pragma unroll
                for (int c = 0; c < 8; c++)
                    acc[r][c] += hreg[r] * wreg[c];
        }
    }

    #pragma unroll
    for (int r = 0; r < 8; r++) {
        int gr = row0 + tr * 8 + r;
        if (gr < N) {
            float dn = dinv[gr];
            #pragma unroll
            for (int c = 0; c < 8; c++) acc[r][c] *= dn;
            *reinterpret_cast<float4*>(&out[gr * NCH + tc * 8])     = *reinterpret_cast<float4*>(&acc[r][0]);
            *reinterpret_cast<float4*>(&out[gr * NCH + tc * 8 + 4]) = *reinterpret_cast<float4*>(&acc[r][4]);
        }
    }
}

// -------- gather: out[n] = relu(dinv[n]*(hws[n] + sum_edges hws[s]) + b) --
// 1 wave per node, float2 per lane.

__global__ __launch_bounds__(256) void k_gather(const float* __restrict__ hws,
                                                const float* __restrict__ bias,
                                                const int* __restrict__ row_start,
                                                const int* __restrict__ edge_src,
                                                const float* __restrict__ dinv,
                                                float* __restrict__ out, int N) {
    int wv = threadIdx.x >> 6;
    int lane = threadIdx.x & 63;
    int n = blockIdx.x * 4 + wv;
    if (n >= N) return;
    const float2* h2 = reinterpret_cast<const float2*>(hws);
    float2 self = h2[(size_t)n * 64 + lane];
    float ax = self.x, ay = self.y;
    int j0 = row_start[n], j1 = row_start[n + 1];
    int j = j0;
    for (; j + 3 < j1; j += 4) {
        int s0 = edge_src[j + 0], s1 = edge_src[j + 1];
        int s2 = edge_src[j + 2], s3 = edge_src[j + 3];
        float2 a = h2[(size_t)s0 * 64 + lane];
        float2 b = h2[(size_t)s1 * 64 + lane];
        float2 c = h2[(size_t)s2 * 64 + lane];
        float2 d = h2[(size_t)s3 * 64 + lane];
        ax += a.x + b.x + c.x + d.x;
        ay += a.y + b.y + c.y + d.y;
    }
    for (; j < j1; j++) {
        float2 a = h2[(size_t)edge_src[j] * 64 + lane];
        ax += a.x; ay += a.y;
    }
    float dn = dinv[n];
    float2 bb = reinterpret_cast<const float2*>(bias)[lane];
    float2 o;
    o.x = fmaxf(ax * dn + bb.x, 0.0f);
    o.y = fmaxf(ay * dn + bb.y, 0.0f);
    reinterpret_cast<float2*>(out)[(size_t)n * 64 + lane] = o;
}

// ---------------- pooling: 2-phase, 64*SUB blocks then 64 blocks ----------

__global__ __launch_bounds__(256) void k_poolA(const float* __restrict__ h,
                                               const int* __restrict__ gstart,
                                               float* __restrict__ partial) {
    int g = blockIdx.x >> 4;           // / SUB
    int s = blockIdx.x & (SUB - 1);
    int c = threadIdx.x & 127;
    int r = threadIdx.x >> 7;          // 0..1
    int j0 = gstart[g], j1 = gstart[g + 1];
    int len = j1 - j0;
    int chunk = (len + SUB - 1) / SUB;
    int a0 = j0 + s * chunk;
    int a1 = a0 + chunk; if (a1 > j1) a1 = j1;
    float acc = 0.0f;
    for (int j = a0 + r; j < a1; j += 2) acc += h[(size_t)j * NCH + c];
    __shared__ float sh[2][128];
    sh[r][c] = acc;
    __syncthreads();
    if (r == 0) partial[(size_t)(g * SUB + s) * NCH + c] = sh[0][c] + sh[1][c];
}

__global__ __launch_bounds__(128) void k_poolB(const float* __restrict__ partial,
                                               const int* __restrict__ gstart,
                                               float* __restrict__ pooled) {
    int g = blockIdx.x;
    int c = threadIdx.x;
    float s = 0.0f;
    #pragma unroll
    for (int i = 0; i < SUB; i++) s += partial[(size_t)(g * SUB + i) * NCH + c];
    int len = gstart[g + 1] - gstart[g];
    pooled[g * NCH + c] = s / fmaxf((float)len, 1.0f);
}

__global__ __launch_bounds__(128) void k_final(const float* __restrict__ pooled,
                                               const float* __restrict__ Wc,
                                               const float* __restrict__ bc,
                                               float* __restrict__ out) {
    int t = threadIdx.x;           // 128 threads: 64 graphs x 2 outs
    int g = t >> 1, o = t & 1;
    float s = 0.0f;
    for (int k = 0; k < NCH; k++) s += pooled[g * NCH + k] * Wc[k * 2 + o];
    out[g * 2 + o] = s + bc[o];
}

// ---------------- launcher ----------------

extern "C" void kernel_launch(void* const* d_in, const int* in_sizes, int n_in,
                              void* d_out, int out_size, void* d_ws, size_t ws_size,
                              hipStream_t stream) {
    const float* x   = (const float*)d_in[0];
    const int* eidx  = (const int*)d_in[1];
    const int* batch = (const int*)d_in[2];
    const float* W1 = (const float*)d_in[3];
    const float* b1 = (const float*)d_in[4];
    const float* W2 = (const float*)d_in[5];
    const float* b2 = (const float*)d_in[6];
    const float* W3 = (const float*)d_in[7];
    const float* b3 = (const float*)d_in[8];
    const float* Wc = (const float*)d_in[9];
    const float* bc = (const float*)d_in[10];
    float* out = (float*)d_out;

    int N = in_sizes[0] / NCH;
    int E = in_sizes[1] / 2;
    const int* src = eidx;
    const int* dst = eidx + E;

    // workspace carve-out (512B aligned)
    char* w = (char*)d_ws;
    auto alloc = [&](size_t bytes) -> void* {
        void* p = (void*)w;
        w += (bytes + 511) & ~(size_t)511;
        return p;
    };
    int nb = (N + 1023) / 1024;
    int*   cnt       = (int*)alloc((size_t)N * 4);
    int*   row_start = (int*)alloc((size_t)(N + 1) * 4);
    int*   cursor    = (int*)alloc((size_t)N * 4);
    int*   blocksum  = (int*)alloc((size_t)nb * 4);
    int*   blockoff  = (int*)alloc((size_t)nb * 4);
    int*   edge_src  = (int*)alloc((size_t)E * 4);
    float* dinv      = (float*)alloc((size_t)N * 4);
    float* hw        = (float*)alloc((size_t)N * NCH * 4);
    float* hA        = (float*)alloc((size_t)N * NCH * 4);
    float* hB        = (float*)alloc((size_t)N * NCH * 4);
    float* partial   = (float*)alloc((size_t)NGRAPH * SUB * NCH * 4);
    float* pooled    = (float*)alloc((size_t)NGRAPH * NCH * 4);
    int*   gstart    = (int*)alloc((size_t)(NGRAPH + 1) * 4);

    hipMemsetAsync(cnt, 0, (size_t)N * 4, stream);

    int gE = (E + 255) / 256;
    int gN = (N + 255) / 256;

    k_count<<<gE, 256, 0, stream>>>(dst, cnt, E);
    k_scanA<<<nb, 256, 0, stream>>>(cnt, blocksum, N);
    k_scanB<<<1, 64, 0, stream>>>(blocksum, blockoff, row_start, nb, N);
    k_scanC<<<nb, 256, 0, stream>>>(cnt, blockoff, row_start, N);
    k_dinv<<<gN, 256, 0, stream>>>(cnt, dinv, N);
    hipMemcpyAsync(cursor, row_start, (size_t)N * 4, hipMemcpyDeviceToDevice, stream);
    k_fill<<<gE, 256, 0, stream>>>(src, dst, cursor, edge_src, E);
    k_gstart<<<gN, 256, 0, stream>>>(batch, gstart, N);

    int gG = (N + 127) / 128;
    int gA = (N + 3) / 4;
    // layer 1
    k_gemm<<<gG, 256, 0, stream>>>(x, W1, dinv, hw, N);
    k_gather<<<gA, 256, 0, stream>>>(hw, b1, row_start, edge_src, dinv, hA, N);
    // layer 2
    k_gemm<<<gG, 256, 0, stream>>>(hA, W2, dinv, hw, N);
    k_gather<<<gA, 256, 0, stream>>>(hw, b2, row_start, edge_src, dinv, hB, N);
    // layer 3
    k_gemm<<<gG, 256, 0, stream>>>(hB, W3, dinv, hw, N);
    k_gather<<<gA, 256, 0, stream>>>(hw, b3, row_start, edge_src, dinv, hA, N);

    k_poolA<<<NGRAPH * SUB, 256, 0, stream>>>(hA, gstart, partial);
    k_poolB<<<NGRAPH, 128, 0, stream>>>(partial, gstart, pooled);
    k_final<<<1, 128, 0, stream>>>(pooled, Wc, bc, out);
}

// Round 7
// 417.979 us; speedup vs baseline: 2.7060x; 1.1250x over previous
//
#include <hip/hip_runtime.h>

#define NCH 128
#define NGRAPH 64
#define SUB 16

// ---------------- CSR build ----------------

__global__ void k_count(const int* __restrict__ dst, int* __restrict__ cnt, int E) {
    int e = blockIdx.x * blockDim.x + threadIdx.x;
    if (e < E) atomicAdd(&cnt[dst[e]], 1);
}

// ---- 3-phase parallel exclusive scan over cnt[N] -> row_start[N+1] ----

__global__ __launch_bounds__(256) void k_scanA(const int* __restrict__ cnt,
                                               int* __restrict__ blocksum, int N) {
    int base = blockIdx.x * 1024 + threadIdx.x * 4;
    int s = 0;
    #pragma unroll
    for (int i = 0; i < 4; i++) { int idx = base + i; if (idx < N) s += cnt[idx]; }
    for (int off = 32; off; off >>= 1) s += __shfl_down(s, off, 64);
    __shared__ int red[4];
    int lane = threadIdx.x & 63, wv = threadIdx.x >> 6;
    if (lane == 0) red[wv] = s;
    __syncthreads();
    if (threadIdx.x == 0) blocksum[blockIdx.x] = red[0] + red[1] + red[2] + red[3];
}

__global__ __launch_bounds__(64) void k_scanB(const int* __restrict__ blocksum,
                                              int* __restrict__ blockoff,
                                              int* __restrict__ row_start, int nb, int N) {
    int t = threadIdx.x;
    int v = (t < nb) ? blocksum[t] : 0;
    int orig = v;
    for (int off = 1; off < 64; off <<= 1) {
        int u = __shfl_up(v, off, 64);
        if (t >= off) v += u;
    }
    if (t < nb) blockoff[t] = v - orig;
    if (t == 63) row_start[N] = v;
}

__global__ __launch_bounds__(256) void k_scanC(const int* __restrict__ cnt,
                                               const int* __restrict__ blockoff,
                                               int* __restrict__ row_start, int N) {
    int t = threadIdx.x;
    int base = blockIdx.x * 1024 + t * 4;
    int v[4];
    #pragma unroll
    for (int i = 0; i < 4; i++) { int idx = base + i; v[i] = (idx < N) ? cnt[idx] : 0; }
    int tsum = v[0] + v[1] + v[2] + v[3];
    int sc = tsum;
    int lane = t & 63, wv = t >> 6;
    for (int off = 1; off < 64; off <<= 1) {
        int u = __shfl_up(sc, off, 64);
        if (lane >= off) sc += u;
    }
    int excl = sc - tsum;
    __shared__ int wsum[4];
    if (lane == 63) wsum[wv] = sc;
    __syncthreads();
    int woff = 0;
    for (int i = 0; i < wv; i++) woff += wsum[i];
    int off0 = blockoff[blockIdx.x] + woff + excl;
    #pragma unroll
    for (int i = 0; i < 4; i++) {
        int idx = base + i;
        if (idx < N) row_start[idx] = off0;
        off0 += v[i];
    }
}

__global__ void k_dinv(const int* __restrict__ cnt, float* __restrict__ dinv, int N) {
    int i = blockIdx.x * blockDim.x + threadIdx.x;
    if (i < N) dinv[i] = rsqrtf((float)cnt[i] + 1.0f);
}

// scatter only the source index (single 4B store per edge)
__global__ void k_fill(const int* __restrict__ src, const int* __restrict__ dst,
                       int* __restrict__ cursor, int* __restrict__ edge_src, int E) {
    int e = blockIdx.x * blockDim.x + threadIdx.x;
    if (e < E) {
        int p = atomicAdd(&cursor[dst[e]], 1);
        edge_src[p] = src[e];
    }
}

// ---------------- graph segment starts (batch is sorted -> no atomics) ----

__global__ void k_gstart(const int* __restrict__ batch, int* __restrict__ gstart, int N) {
    int i = blockIdx.x * blockDim.x + threadIdx.x;
    if (i >= N) return;
    int b = batch[i];
    int prev = (i == 0) ? -1 : batch[i - 1];
    for (int g = prev + 1; g <= b; g++) gstart[g] = i;
    if (i == N - 1) {
        for (int g = b + 1; g <= NGRAPH; g++) gstart[g] = N;
    }
}

// ------- GEMM: hwb[N,128](bf16) = dinv[r] * (H[N,128] @ W[128,128]) -------
// 128x128 tile per block, 256 threads, 8x8 register tile per thread.
// Epilogue folds the row dinv scale AND packs to bf16 (halves gather bytes).

#define KT 32

__device__ __forceinline__ unsigned bf16rne(float f) {
    unsigned u = __float_as_uint(f);
    u += 0x7fffu + ((u >> 16) & 1u);
    return u >> 16;
}

__global__ __launch_bounds__(256) void k_gemm(const float* __restrict__ H,
                                              const float* __restrict__ W,
                                              const float* __restrict__ dinv,
                                              unsigned* __restrict__ hwb, int N) {
    __shared__ float Ht[KT][132];
    __shared__ float Wl[KT][128];
    int t = threadIdx.x;
    int row0 = blockIdx.x * 128;
    int tc = t & 15, tr = t >> 4;      // 16x16 thread grid

    float acc[8][8];
    #pragma unroll
    for (int r = 0; r < 8; r++)
        #pragma unroll
        for (int c = 0; c < 8; c++) acc[r][c] = 0.0f;

    for (int kt = 0; kt < 128; kt += KT) {
        __syncthreads();
        #pragma unroll
        for (int i = 0; i < 4; i++) {
            int l = (i * 256 + t) * 4;        // 0..4095
            int r = l >> 5;
            int kk = l & 31;
            int gr = row0 + r;
            float4 v = make_float4(0.f, 0.f, 0.f, 0.f);
            if (gr < N) v = *reinterpret_cast<const float4*>(&H[gr * NCH + kt + kk]);
            Ht[kk + 0][r] = v.x;
            Ht[kk + 1][r] = v.y;
            Ht[kk + 2][r] = v.z;
            Ht[kk + 3][r] = v.w;
        }
        #pragma unroll
        for (int i = 0; i < 4; i++) {
            int l = (i * 256 + t) * 4;
            int kk = l >> 7;
            int c = l & 127;
            *reinterpret_cast<float4*>(&Wl[kk][c]) =
                *reinterpret_cast<const float4*>(&W[(kt + kk) * NCH + c]);
        }
        __syncthreads();
        #pragma unroll
        for (int k = 0; k < KT; k++) {
            float hreg[8], wreg[8];
            *reinterpret_cast<float4*>(&hreg[0]) = *reinterpret_cast<const float4*>(&Ht[k][tr * 8]);
            *reinterpret_cast<float4*>(&hreg[4]) = *reinterpret_cast<const float4*>(&Ht[k][tr * 8 + 4]);
            *reinterpret_cast<float4*>(&wreg[0]) = *reinterpret_cast<const float4*>(&Wl[k][tc * 8]);
            *reinterpret_cast<float4*>(&wreg[4]) = *reinterpret_cast<const float4*>(&Wl[k][tc * 8 + 4]);
            #pragma unroll
            for (int r = 0; r < 8; r++)
                #pragma unroll
                for (int c = 0; c < 8; c++)
                    acc[r][c] += hreg[r] * wreg[c];
        }
    }

    #pragma unroll
    for (int r = 0; r < 8; r++) {
        int gr = row0 + tr * 8 + r;
        if (gr < N) {
            float dn = dinv[gr];
            uint4 pk;
            unsigned* p = &pk.x;
            #pragma unroll
            for (int c = 0; c < 4; c++) {
                unsigned lo = bf16rne(acc[r][2 * c] * dn);
                unsigned hi = bf16rne(acc[r][2 * c + 1] * dn);
                p[c] = lo | (hi << 16);
            }
            // row = 64 uints; thread covers uints tc*4 .. tc*4+3
            *reinterpret_cast<uint4*>(&hwb[(size_t)gr * 64 + tc * 4]) = pk;
        }
    }
}

// -- gather: out[n] = relu(dinv[n]*(hws[n] + sum_e hws[src]) + b), bf16 in --
// 1 wave per node; lane holds 2 channels (1 uint = 2 bf16 per row).

__global__ __launch_bounds__(256) void k_gather(const unsigned* __restrict__ hwb,
                                                const float* __restrict__ bias,
                                                const int* __restrict__ row_start,
                                                const int* __restrict__ edge_src,
                                                const float* __restrict__ dinv,
                                                float* __restrict__ out, int N) {
    int wv = threadIdx.x >> 6;
    int lane = threadIdx.x & 63;
    int n = blockIdx.x * 4 + wv;
    if (n >= N) return;
    unsigned v = hwb[(size_t)n * 64 + lane];
    float ax = __uint_as_float(v << 16);
    float ay = __uint_as_float(v & 0xffff0000u);
    int j0 = row_start[n], j1 = row_start[n + 1];
    int j = j0;
    for (; j + 3 < j1; j += 4) {
        int s0 = edge_src[j + 0], s1 = edge_src[j + 1];
        int s2 = edge_src[j + 2], s3 = edge_src[j + 3];
        unsigned a = hwb[(size_t)s0 * 64 + lane];
        unsigned b = hwb[(size_t)s1 * 64 + lane];
        unsigned c = hwb[(size_t)s2 * 64 + lane];
        unsigned d = hwb[(size_t)s3 * 64 + lane];
        ax += __uint_as_float(a << 16) + __uint_as_float(b << 16)
            + __uint_as_float(c << 16) + __uint_as_float(d << 16);
        ay += __uint_as_float(a & 0xffff0000u) + __uint_as_float(b & 0xffff0000u)
            + __uint_as_float(c & 0xffff0000u) + __uint_as_float(d & 0xffff0000u);
    }
    for (; j < j1; j++) {
        unsigned a = hwb[(size_t)edge_src[j] * 64 + lane];
        ax += __uint_as_float(a << 16);
        ay += __uint_as_float(a & 0xffff0000u);
    }
    float dn = dinv[n];
    float2 bb = reinterpret_cast<const float2*>(bias)[lane];
    float2 o;
    o.x = fmaxf(ax * dn + bb.x, 0.0f);
    o.y = fmaxf(ay * dn + bb.y, 0.0f);
    reinterpret_cast<float2*>(out)[(size_t)n * 64 + lane] = o;
}

// ---------------- pooling: 2-phase, 64*SUB blocks then 64 blocks ----------

__global__ __launch_bounds__(256) void k_poolA(const float* __restrict__ h,
                                               const int* __restrict__ gstart,
                                               float* __restrict__ partial) {
    int g = blockIdx.x >> 4;           // / SUB
    int s = blockIdx.x & (SUB - 1);
    int c = threadIdx.x & 127;
    int r = threadIdx.x >> 7;          // 0..1
    int j0 = gstart[g], j1 = gstart[g + 1];
    int len = j1 - j0;
    int chunk = (len + SUB - 1) / SUB;
    int a0 = j0 + s * chunk;
    int a1 = a0 + chunk; if (a1 > j1) a1 = j1;
    float acc = 0.0f;
    for (int j = a0 + r; j < a1; j += 2) acc += h[(size_t)j * NCH + c];
    __shared__ float sh[2][128];
    sh[r][c] = acc;
    __syncthreads();
    if (r == 0) partial[(size_t)(g * SUB + s) * NCH + c] = sh[0][c] + sh[1][c];
}

__global__ __launch_bounds__(128) void k_poolB(const float* __restrict__ partial,
                                               const int* __restrict__ gstart,
                                               float* __restrict__ pooled) {
    int g = blockIdx.x;
    int c = threadIdx.x;
    float s = 0.0f;
    #pragma unroll
    for (int i = 0; i < SUB; i++) s += partial[(size_t)(g * SUB + i) * NCH + c];
    int len = gstart[g + 1] - gstart[g];
    pooled[g * NCH + c] = s / fmaxf((float)len, 1.0f);
}

__global__ __launch_bounds__(128) void k_final(const float* __restrict__ pooled,
                                               const float* __restrict__ Wc,
                                               const float* __restrict__ bc,
                                               float* __restrict__ out) {
    int t = threadIdx.x;           // 128 threads: 64 graphs x 2 outs
    int g = t >> 1, o = t & 1;
    float s = 0.0f;
    for (int k = 0; k < NCH; k++) s += pooled[g * NCH + k] * Wc[k * 2 + o];
    out[g * 2 + o] = s + bc[o];
}

// ---------------- launcher ----------------

extern "C" void kernel_launch(void* const* d_in, const int* in_sizes, int n_in,
                              void* d_out, int out_size, void* d_ws, size_t ws_size,
                              hipStream_t stream) {
    const float* x   = (const float*)d_in[0];
    const int* eidx  = (const int*)d_in[1];
    const int* batch = (const int*)d_in[2];
    const float* W1 = (const float*)d_in[3];
    const float* b1 = (const float*)d_in[4];
    const float* W2 = (const float*)d_in[5];
    const float* b2 = (const float*)d_in[6];
    const float* W3 = (const float*)d_in[7];
    const float* b3 = (const float*)d_in[8];
    const float* Wc = (const float*)d_in[9];
    const float* bc = (const float*)d_in[10];
    float* out = (float*)d_out;

    int N = in_sizes[0] / NCH;
    int E = in_sizes[1] / 2;
    const int* src = eidx;
    const int* dst = eidx + E;

    // workspace carve-out (512B aligned)
    char* w = (char*)d_ws;
    auto alloc = [&](size_t bytes) -> void* {
        void* p = (void*)w;
        w += (bytes + 511) & ~(size_t)511;
        return p;
    };
    int nb = (N + 1023) / 1024;
    int*      cnt       = (int*)alloc((size_t)N * 4);
    int*      row_start = (int*)alloc((size_t)(N + 1) * 4);
    int*      cursor    = (int*)alloc((size_t)N * 4);
    int*      blocksum  = (int*)alloc((size_t)nb * 4);
    int*      blockoff  = (int*)alloc((size_t)nb * 4);
    int*      edge_src  = (int*)alloc((size_t)E * 4);
    float*    dinv      = (float*)alloc((size_t)N * 4);
    unsigned* hwb       = (unsigned*)alloc((size_t)N * 64 * 4);   // bf16 x128
    float*    hA        = (float*)alloc((size_t)N * NCH * 4);
    float*    hB        = (float*)alloc((size_t)N * NCH * 4);
    float*    partial   = (float*)alloc((size_t)NGRAPH * SUB * NCH * 4);
    float*    pooled    = (float*)alloc((size_t)NGRAPH * NCH * 4);
    int*      gstart    = (int*)alloc((size_t)(NGRAPH + 1) * 4);

    hipMemsetAsync(cnt, 0, (size_t)N * 4, stream);

    int gE = (E + 255) / 256;
    int gN = (N + 255) / 256;

    k_count<<<gE, 256, 0, stream>>>(dst, cnt, E);
    k_scanA<<<nb, 256, 0, stream>>>(cnt, blocksum, N);
    k_scanB<<<1, 64, 0, stream>>>(blocksum, blockoff, row_start, nb, N);
    k_scanC<<<nb, 256, 0, stream>>>(cnt, blockoff, row_start, N);
    k_dinv<<<gN, 256, 0, stream>>>(cnt, dinv, N);
    hipMemcpyAsync(cursor, row_start, (size_t)N * 4, hipMemcpyDeviceToDevice, stream);
    k_fill<<<gE, 256, 0, stream>>>(src, dst, cursor, edge_src, E);
    k_gstart<<<gN, 256, 0, stream>>>(batch, gstart, N);

    int gG = (N + 127) / 128;
    int gA = (N + 3) / 4;
    // layer 1
    k_gemm<<<gG, 256, 0, stream>>>(x, W1, dinv, hwb, N);
    k_gather<<<gA, 256, 0, stream>>>(hwb, b1, row_start, edge_src, dinv, hA, N);
    // layer 2
    k_gemm<<<gG, 256, 0, stream>>>(hA, W2, dinv, hwb, N);
    k_gather<<<gA, 256, 0, stream>>>(hwb, b2, row_start, edge_src, dinv, hB, N);
    // layer 3
    k_gemm<<<gG, 256, 0, stream>>>(hB, W3, dinv, hwb, N);
    k_gather<<<gA, 256, 0, stream>>>(hwb, b3, row_start, edge_src, dinv, hA, N);

    k_poolA<<<NGRAPH * SUB, 256, 0, stream>>>(hA, gstart, partial);
    k_poolB<<<NGRAPH, 128, 0, stream>>>(partial, gstart, pooled);
    k_final<<<1, 128, 0, stream>>>(pooled, Wc, bc, out);
}

// Round 8
// 406.415 us; speedup vs baseline: 2.7830x; 1.0285x over previous
//
#include <hip/hip_runtime.h>

#define NCH 128
#define NGRAPH 64
#define SUB 16

// ---------------- CSR build ----------------

__global__ void k_count(const int* __restrict__ dst, int* __restrict__ cnt, int E) {
    int e = blockIdx.x * blockDim.x + threadIdx.x;
    if (e < E) atomicAdd(&cnt[dst[e]], 1);
}

// ---- 3-phase parallel exclusive scan over cnt[N] -> row_start[N+1] ----

__global__ __launch_bounds__(256) void k_scanA(const int* __restrict__ cnt,
                                               int* __restrict__ blocksum, int N) {
    int base = blockIdx.x * 1024 + threadIdx.x * 4;
    int s = 0;
    #pragma unroll
    for (int i = 0; i < 4; i++) { int idx = base + i; if (idx < N) s += cnt[idx]; }
    for (int off = 32; off; off >>= 1) s += __shfl_down(s, off, 64);
    __shared__ int red[4];
    int lane = threadIdx.x & 63, wv = threadIdx.x >> 6;
    if (lane == 0) red[wv] = s;
    __syncthreads();
    if (threadIdx.x == 0) blocksum[blockIdx.x] = red[0] + red[1] + red[2] + red[3];
}

__global__ __launch_bounds__(64) void k_scanB(const int* __restrict__ blocksum,
                                              int* __restrict__ blockoff,
                                              int* __restrict__ row_start, int nb, int N) {
    int t = threadIdx.x;
    int v = (t < nb) ? blocksum[t] : 0;
    int orig = v;
    for (int off = 1; off < 64; off <<= 1) {
        int u = __shfl_up(v, off, 64);
        if (t >= off) v += u;
    }
    if (t < nb) blockoff[t] = v - orig;
    if (t == 63) row_start[N] = v;
}

__global__ __launch_bounds__(256) void k_scanC(const int* __restrict__ cnt,
                                               const int* __restrict__ blockoff,
                                               int* __restrict__ row_start, int N) {
    int t = threadIdx.x;
    int base = blockIdx.x * 1024 + t * 4;
    int v[4];
    #pragma unroll
    for (int i = 0; i < 4; i++) { int idx = base + i; v[i] = (idx < N) ? cnt[idx] : 0; }
    int tsum = v[0] + v[1] + v[2] + v[3];
    int sc = tsum;
    int lane = t & 63, wv = t >> 6;
    for (int off = 1; off < 64; off <<= 1) {
        int u = __shfl_up(sc, off, 64);
        if (lane >= off) sc += u;
    }
    int excl = sc - tsum;
    __shared__ int wsum[4];
    if (lane == 63) wsum[wv] = sc;
    __syncthreads();
    int woff = 0;
    for (int i = 0; i < wv; i++) woff += wsum[i];
    int off0 = blockoff[blockIdx.x] + woff + excl;
    #pragma unroll
    for (int i = 0; i < 4; i++) {
        int idx = base + i;
        if (idx < N) row_start[idx] = off0;
        off0 += v[i];
    }
}

__global__ void k_dinv(const int* __restrict__ cnt, float* __restrict__ dinv, int N) {
    int i = blockIdx.x * blockDim.x + threadIdx.x;
    if (i < N) dinv[i] = rsqrtf((float)cnt[i] + 1.0f);
}

// XCD-localized scatter: 8 dst-ranges, range = blockIdx&7 so (under the
// round-robin block->XCD heuristic) each edge_src cache line is written by
// one XCD only. Edge list is re-read 8x but LLC absorbs it.
__global__ __launch_bounds__(256) void k_fill(const int* __restrict__ src,
                                              const int* __restrict__ dst,
                                              int* __restrict__ cursor,
                                              int* __restrict__ edge_src, int E, int N) {
    int range = blockIdx.x & 7;
    int chunk = blockIdx.x >> 3;
    int r0 = (range * N) >> 3;
    int r1 = ((range + 1) * N) >> 3;
    int e = chunk * 256 + threadIdx.x;
    if (e >= E) return;
    int d = dst[e];
    if (d >= r0 && d < r1) {
        int p = atomicAdd(&cursor[d], 1);
        edge_src[p] = src[e];
    }
}

// ---------------- graph segment starts (batch is sorted -> no atomics) ----

__global__ void k_gstart(const int* __restrict__ batch, int* __restrict__ gstart, int N) {
    int i = blockIdx.x * blockDim.x + threadIdx.x;
    if (i >= N) return;
    int b = batch[i];
    int prev = (i == 0) ? -1 : batch[i - 1];
    for (int g = prev + 1; g <= b; g++) gstart[g] = i;
    if (i == N - 1) {
        for (int g = b + 1; g <= NGRAPH; g++) gstart[g] = N;
    }
}

// ------- GEMM: hwb[N,128](bf16) = dinv[r] * (H[N,128] @ W[128,128]) -------

#define KT 32

__device__ __forceinline__ unsigned bf16rne(float f) {
    unsigned u = __float_as_uint(f);
    u += 0x7fffu + ((u >> 16) & 1u);
    return u >> 16;
}

__global__ __launch_bounds__(256) void k_gemm(const float* __restrict__ H,
                                              const float* __restrict__ W,
                                              const float* __restrict__ dinv,
                                              unsigned* __restrict__ hwb, int N) {
    __shared__ float Ht[KT][132];
    __shared__ float Wl[KT][128];
    int t = threadIdx.x;
    int row0 = blockIdx.x * 128;
    int tc = t & 15, tr = t >> 4;      // 16x16 thread grid

    float acc[8][8];
    #pragma unroll
    for (int r = 0; r < 8; r++)
        #pragma unroll
        for (int c = 0; c < 8; c++) acc[r][c] = 0.0f;

    for (int kt = 0; kt < 128; kt += KT) {
        __syncthreads();
        #pragma unroll
        for (int i = 0; i < 4; i++) {
            int l = (i * 256 + t) * 4;        // 0..4095
            int r = l >> 5;
            int kk = l & 31;
            int gr = row0 + r;
            float4 v = make_float4(0.f, 0.f, 0.f, 0.f);
            if (gr < N) v = *reinterpret_cast<const float4*>(&H[gr * NCH + kt + kk]);
            Ht[kk + 0][r] = v.x;
            Ht[kk + 1][r] = v.y;
            Ht[kk + 2][r] = v.z;
            Ht[kk + 3][r] = v.w;
        }
        #pragma unroll
        for (int i = 0; i < 4; i++) {
            int l = (i * 256 + t) * 4;
            int kk = l >> 7;
            int c = l & 127;
            *reinterpret_cast<float4*>(&Wl[kk][c]) =
                *reinterpret_cast<const float4*>(&W[(kt + kk) * NCH + c]);
        }
        __syncthreads();
        #pragma unroll
        for (int k = 0; k < KT; k++) {
            float hreg[8], wreg[8];
            *reinterpret_cast<float4*>(&hreg[0]) = *reinterpret_cast<const float4*>(&Ht[k][tr * 8]);
            *reinterpret_cast<float4*>(&hreg[4]) = *reinterpret_cast<const float4*>(&Ht[k][tr * 8 + 4]);
            *reinterpret_cast<float4*>(&wreg[0]) = *reinterpret_cast<const float4*>(&Wl[k][tc * 8]);
            *reinterpret_cast<float4*>(&wreg[4]) = *reinterpret_cast<const float4*>(&Wl[k][tc * 8 + 4]);
            #pragma unroll
            for (int r = 0; r < 8; r++)
                #pragma unroll
                for (int c = 0; c < 8; c++)
                    acc[r][c] += hreg[r] * wreg[c];
        }
    }

    #pragma unroll
    for (int r = 0; r < 8; r++) {
        int gr = row0 + tr * 8 + r;
        if (gr < N) {
            float dn = dinv[gr];
            uint4 pk;
            unsigned* p = &pk.x;
            #pragma unroll
            for (int c = 0; c < 4; c++) {
                unsigned lo = bf16rne(acc[r][2 * c] * dn);
                unsigned hi = bf16rne(acc[r][2 * c + 1] * dn);
                p[c] = lo | (hi << 16);
            }
            *reinterpret_cast<uint4*>(&hwb[(size_t)gr * 64 + tc * 4]) = pk;
        }
    }
}

// -- gather: out[n] = relu(dinv[n]*(hws[n] + sum_e hws[src]) + b), bf16 in --

__global__ __launch_bounds__(256) void k_gather(const unsigned* __restrict__ hwb,
                                                const float* __restrict__ bias,
                                                const int* __restrict__ row_start,
                                                const int* __restrict__ edge_src,
                                                const float* __restrict__ dinv,
                                                float* __restrict__ out, int N) {
    int wv = threadIdx.x >> 6;
    int lane = threadIdx.x & 63;
    int n = blockIdx.x * 4 + wv;
    if (n >= N) return;
    unsigned v = hwb[(size_t)n * 64 + lane];
    float ax = __uint_as_float(v << 16);
    float ay = __uint_as_float(v & 0xffff0000u);
    int j0 = row_start[n], j1 = row_start[n + 1];
    int j = j0;
    for (; j + 3 < j1; j += 4) {
        int s0 = edge_src[j + 0], s1 = edge_src[j + 1];
        int s2 = edge_src[j + 2], s3 = edge_src[j + 3];
        unsigned a = hwb[(size_t)s0 * 64 + lane];
        unsigned b = hwb[(size_t)s1 * 64 + lane];
        unsigned c = hwb[(size_t)s2 * 64 + lane];
        unsigned d = hwb[(size_t)s3 * 64 + lane];
        ax += __uint_as_float(a << 16) + __uint_as_float(b << 16)
            + __uint_as_float(c << 16) + __uint_as_float(d << 16);
        ay += __uint_as_float(a & 0xffff0000u) + __uint_as_float(b & 0xffff0000u)
            + __uint_as_float(c & 0xffff0000u) + __uint_as_float(d & 0xffff0000u);
    }
    for (; j < j1; j++) {
        unsigned a = hwb[(size_t)edge_src[j] * 64 + lane];
        ax += __uint_as_float(a << 16);
        ay += __uint_as_float(a & 0xffff0000u);
    }
    float dn = dinv[n];
    float2 bb = reinterpret_cast<const float2*>(bias)[lane];
    float2 o;
    o.x = fmaxf(ax * dn + bb.x, 0.0f);
    o.y = fmaxf(ay * dn + bb.y, 0.0f);
    reinterpret_cast<float2*>(out)[(size_t)n * 64 + lane] = o;
}

// ---------------- pooling: 2-phase, 64*SUB blocks then 64 blocks ----------

__global__ __launch_bounds__(256) void k_poolA(const float* __restrict__ h,
                                               const int* __restrict__ gstart,
                                               float* __restrict__ partial) {
    int g = blockIdx.x >> 4;           // / SUB
    int s = blockIdx.x & (SUB - 1);
    int c = threadIdx.x & 127;
    int r = threadIdx.x >> 7;          // 0..1
    int j0 = gstart[g], j1 = gstart[g + 1];
    int len = j1 - j0;
    int chunk = (len + SUB - 1) / SUB;
    int a0 = j0 + s * chunk;
    int a1 = a0 + chunk; if (a1 > j1) a1 = j1;
    float acc = 0.0f;
    for (int j = a0 + r; j < a1; j += 2) acc += h[(size_t)j * NCH + c];
    __shared__ float sh[2][128];
    sh[r][c] = acc;
    __syncthreads();
    if (r == 0) partial[(size_t)(g * SUB + s) * NCH + c] = sh[0][c] + sh[1][c];
}

__global__ __launch_bounds__(128) void k_poolB(const float* __restrict__ partial,
                                               const int* __restrict__ gstart,
                                               float* __restrict__ pooled) {
    int g = blockIdx.x;
    int c = threadIdx.x;
    float s = 0.0f;
    #pragma unroll
    for (int i = 0; i < SUB; i++) s += partial[(size_t)(g * SUB + i) * NCH + c];
    int len = gstart[g + 1] - gstart[g];
    pooled[g * NCH + c] = s / fmaxf((float)len, 1.0f);
}

__global__ __launch_bounds__(128) void k_final(const float* __restrict__ pooled,
                                               const float* __restrict__ Wc,
                                               const float* __restrict__ bc,
                                               float* __restrict__ out) {
    int t = threadIdx.x;           // 128 threads: 64 graphs x 2 outs
    int g = t >> 1, o = t & 1;
    float s = 0.0f;
    for (int k = 0; k < NCH; k++) s += pooled[g * NCH + k] * Wc[k * 2 + o];
    out[g * 2 + o] = s + bc[o];
}

// ---------------- launcher ----------------

extern "C" void kernel_launch(void* const* d_in, const int* in_sizes, int n_in,
                              void* d_out, int out_size, void* d_ws, size_t ws_size,
                              hipStream_t stream) {
    const float* x   = (const float*)d_in[0];
    const int* eidx  = (const int*)d_in[1];
    const int* batch = (const int*)d_in[2];
    const float* W1 = (const float*)d_in[3];
    const float* b1 = (const float*)d_in[4];
    const float* W2 = (const float*)d_in[5];
    const float* b2 = (const float*)d_in[6];
    const float* W3 = (const float*)d_in[7];
    const float* b3 = (const float*)d_in[8];
    const float* Wc = (const float*)d_in[9];
    const float* bc = (const float*)d_in[10];
    float* out = (float*)d_out;

    int N = in_sizes[0] / NCH;
    int E = in_sizes[1] / 2;
    const int* src = eidx;
    const int* dst = eidx + E;

    // workspace carve-out (512B aligned)
    char* w = (char*)d_ws;
    auto alloc = [&](size_t bytes) -> void* {
        void* p = (void*)w;
        w += (bytes + 511) & ~(size_t)511;
        return p;
    };
    int nb = (N + 1023) / 1024;
    int*      cnt       = (int*)alloc((size_t)N * 4);
    int*      row_start = (int*)alloc((size_t)(N + 1) * 4);
    int*      cursor    = (int*)alloc((size_t)N * 4);
    int*      blocksum  = (int*)alloc((size_t)nb * 4);
    int*      blockoff  = (int*)alloc((size_t)nb * 4);
    int*      edge_src  = (int*)alloc((size_t)E * 4);
    float*    dinv      = (float*)alloc((size_t)N * 4);
    unsigned* hwb       = (unsigned*)alloc((size_t)N * 64 * 4);   // bf16 x128
    float*    hA        = (float*)alloc((size_t)N * NCH * 4);
    float*    hB        = (float*)alloc((size_t)N * NCH * 4);
    float*    partial   = (float*)alloc((size_t)NGRAPH * SUB * NCH * 4);
    float*    pooled    = (float*)alloc((size_t)NGRAPH * NCH * 4);
    int*      gstart    = (int*)alloc((size_t)(NGRAPH + 1) * 4);

    hipMemsetAsync(cnt, 0, (size_t)N * 4, stream);

    int gE = (E + 255) / 256;
    int gN = (N + 255) / 256;

    k_count<<<gE, 256, 0, stream>>>(dst, cnt, E);
    k_scanA<<<nb, 256, 0, stream>>>(cnt, blocksum, N);
    k_scanB<<<1, 64, 0, stream>>>(blocksum, blockoff, row_start, nb, N);
    k_scanC<<<nb, 256, 0, stream>>>(cnt, blockoff, row_start, N);
    k_dinv<<<gN, 256, 0, stream>>>(cnt, dinv, N);
    hipMemcpyAsync(cursor, row_start, (size_t)N * 4, hipMemcpyDeviceToDevice, stream);
    k_fill<<<gE * 8, 256, 0, stream>>>(src, dst, cursor, edge_src, E, N);
    k_gstart<<<gN, 256, 0, stream>>>(batch, gstart, N);

    int gG = (N + 127) / 128;
    int gA = (N + 3) / 4;
    // layer 1
    k_gemm<<<gG, 256, 0, stream>>>(x, W1, dinv, hwb, N);
    k_gather<<<gA, 256, 0, stream>>>(hwb, b1, row_start, edge_src, dinv, hA, N);
    // layer 2
    k_gemm<<<gG, 256, 0, stream>>>(hA, W2, dinv, hwb, N);
    k_gather<<<gA, 256, 0, stream>>>(hwb, b2, row_start, edge_src, dinv, hB, N);
    // layer 3
    k_gemm<<<gG, 256, 0, stream>>>(hB, W3, dinv, hwb, N);
    k_gather<<<gA, 256, 0, stream>>>(hwb, b3, row_start, edge_src, dinv, hA, N);

    k_poolA<<<NGRAPH * SUB, 256, 0, stream>>>(hA, gstart, partial);
    k_poolB<<<NGRAPH, 128, 0, stream>>>(partial, gstart, pooled);
    k_final<<<1, 128, 0, stream>>>(pooled, Wc, bc, out);
}